// Round 16
// baseline (152.104 us; speedup 1.0000x reference)
//
#include <hip/hip_runtime.h>
#include <hip/hip_bf16.h>

typedef __attribute__((ext_vector_type(8))) short short8;
typedef __attribute__((ext_vector_type(4))) short short4v;
typedef __attribute__((ext_vector_type(4))) float f32x4;

#define TT 4096
#define DM 1024
#define NH 16
#define NPROJ 1280   // 128 qs + 128 ks + 256 qg + 256 kg + 512 v
#define DATTN 512

static __device__ __forceinline__ short f2bf(float f) {
  __hip_bfloat16 h = __float2bfloat16(f);
  return *reinterpret_cast<short*>(&h);
}
static __device__ __forceinline__ float bfs2f(short s) {
  __hip_bfloat16 h = *reinterpret_cast<__hip_bfloat16*>(&s);
  return __bfloat162float(h);
}

// ---------------- fused prep: x->bf16, ow->bf16, wcat concat (one launch) ----------------
#define NB_X   (TT * DM / 4 / 256)        // 4096 blocks
#define NB_OW  (DM * DATTN / 4 / 256)     // 512 blocks
#define NB_WC  (NPROJ * DM / 4 / 256)     // 1280 blocks
__global__ __launch_bounds__(256) void k_prep(const float* __restrict__ x,
    const float* __restrict__ ow, const float* __restrict__ qs, const float* __restrict__ ks,
    const float* __restrict__ qg, const float* __restrict__ kg, const float* __restrict__ vw,
    __hip_bfloat16* __restrict__ Xbf, __hip_bfloat16* __restrict__ OW,
    __hip_bfloat16* __restrict__ Wcat) {
  const int b = blockIdx.x;
  if (b < NB_X) {
    const int i = b * 256 + threadIdx.x;
    float4 v = reinterpret_cast<const float4*>(x)[i];
    short4v o;
    o[0] = f2bf(v.x); o[1] = f2bf(v.y); o[2] = f2bf(v.z); o[3] = f2bf(v.w);
    reinterpret_cast<short4v*>(Xbf)[i] = o;
  } else if (b < NB_X + NB_OW) {
    const int i = (b - NB_X) * 256 + threadIdx.x;
    float4 v = reinterpret_cast<const float4*>(ow)[i];
    short4v o;
    o[0] = f2bf(v.x); o[1] = f2bf(v.y); o[2] = f2bf(v.z); o[3] = f2bf(v.w);
    reinterpret_cast<short4v*>(OW)[i] = o;
  } else {
    const int i = (b - NB_X - NB_OW) * 256 + threadIdx.x;
    const int idx = i * 4;
    const int row = idx >> 10;
    const int col = idx & 1023;
    const float* src;
    if (row < 128)      src = qs + (size_t)row * DM;
    else if (row < 256) src = ks + (size_t)(row - 128) * DM;
    else if (row < 512) src = qg + (size_t)(row - 256) * DM;
    else if (row < 768) src = kg + (size_t)(row - 512) * DM;
    else                src = vw + (size_t)(row - 768) * DM;
    float4 v = *reinterpret_cast<const float4*>(src + col);
    short4v o;
    o[0] = f2bf(v.x); o[1] = f2bf(v.y); o[2] = f2bf(v.z); o[3] = f2bf(v.w);
    *reinterpret_cast<short4v*>(Wcat + idx) = o;
  }
}

// ---------------- bf16 GEMM, B^T layout, BM=64 BN=128 BK=32, double-buffered ----------
template<int OUT_BF16>
__global__ __launch_bounds__(256) void k_gemm_bt(const __hip_bfloat16* __restrict__ A,
    const __hip_bfloat16* __restrict__ B, void* __restrict__ Cv, int M, int N, int K) {
  __shared__ alignas(16) __hip_bfloat16 lA[2][64 * 32];
  __shared__ alignas(16) __hip_bfloat16 lB[2][128 * 32];
  const int tid = threadIdx.x;
  const int lane = tid & 63;
  const int wid = tid >> 6;
  const int m0 = blockIdx.x * 64, n0 = blockIdx.y * 128;
  const int wm = (wid >> 1) * 32, wn = (wid & 1) * 64;
  const int srow = tid >> 2;          // 0..63
  const int scol = (tid & 3) * 8;     // bf16 elements
  const int fr = lane & 15, fk = (lane >> 4) * 8;
  f32x4 acc[2][4];
  const f32x4 zz = {0.f, 0.f, 0.f, 0.f};
#pragma unroll
  for (int m = 0; m < 2; ++m)
#pragma unroll
    for (int n = 0; n < 4; ++n) acc[m][n] = zz;

  auto stage = [&](int kt, int buf) {
    const __hip_bfloat16* ga0 = A + (size_t)(m0 + srow) * K + kt + scol;
    const __hip_bfloat16* gb0 = B + (size_t)(n0 + srow) * K + kt + scol;
    const __hip_bfloat16* gb1 = B + (size_t)(n0 + 64 + srow) * K + kt + scol;
    __builtin_amdgcn_global_load_lds((const __attribute__((address_space(1))) void*)ga0,
        (__attribute__((address_space(3))) void*)(lA[buf] + srow * 32 + scol), 16, 0, 0);
    __builtin_amdgcn_global_load_lds((const __attribute__((address_space(1))) void*)gb0,
        (__attribute__((address_space(3))) void*)(lB[buf] + srow * 32 + scol), 16, 0, 0);
    __builtin_amdgcn_global_load_lds((const __attribute__((address_space(1))) void*)gb1,
        (__attribute__((address_space(3))) void*)(lB[buf] + (64 + srow) * 32 + scol), 16, 0, 0);
  };
  stage(0, 0);
  int buf = 0;
  for (int kt = 0; kt < K; kt += 32) {
    __syncthreads();   // staging of buf complete; prev reads of buf^1 done
    if (kt + 32 < K) stage(kt + 32, buf ^ 1);
    short8 af[2], bfr[4];
#pragma unroll
    for (int m = 0; m < 2; ++m)
      af[m] = *reinterpret_cast<const short8*>(lA[buf] + (wm + m * 16 + fr) * 32 + fk);
#pragma unroll
    for (int n = 0; n < 4; ++n)
      bfr[n] = *reinterpret_cast<const short8*>(lB[buf] + (wn + n * 16 + fr) * 32 + fk);
#pragma unroll
    for (int m = 0; m < 2; ++m)
#pragma unroll
      for (int n = 0; n < 4; ++n)
        acc[m][n] = __builtin_amdgcn_mfma_f32_16x16x32_bf16(af[m], bfr[n], acc[m][n], 0, 0, 0);
    buf ^= 1;
  }
  const int cr = (lane >> 4) * 4, cc = lane & 15;
#pragma unroll
  for (int m = 0; m < 2; ++m)
#pragma unroll
    for (int n = 0; n < 4; ++n)
#pragma unroll
      for (int j = 0; j < 4; ++j) {
        const int row = m0 + wm + m * 16 + cr + j;
        const int col = n0 + wn + n * 16 + cc;
        if (OUT_BF16)
          ((__hip_bfloat16*)Cv)[(size_t)row * N + col] = __float2bfloat16(acc[m][n][j]);
        else
          ((float*)Cv)[(size_t)row * N + col] = acc[m][n][j];
      }
}

// ---------------- RoPE + pack Q/K (H,T,32) and V^T (H,32,T), vectorized loads ----------
__global__ __launch_bounds__(256) void k_rope_pack(const __hip_bfloat16* __restrict__ proj,
    const float* __restrict__ ls, const int* __restrict__ posp,
    __hip_bfloat16* __restrict__ Qp, __hip_bfloat16* __restrict__ Kp,
    __hip_bfloat16* __restrict__ Vt) {
  const int gid = blockIdx.x * blockDim.x + threadIdx.x;  // T*NH, t fastest
  const int t = gid & (TT - 1);
  const int h = gid >> 12;
  const short8* pr8 = reinterpret_cast<const short8*>(proj + (size_t)t * NPROJ);
  const short8 qs8 = pr8[h];
  const short8 ks8 = pr8[16 + h];
  const short8 qg1 = pr8[32 + 2 * h], qg2 = pr8[33 + 2 * h];
  const short8 kg1 = pr8[64 + 2 * h], kg2 = pr8[65 + 2 * h];
  const short8 vv0 = pr8[96 + 4 * h], vv1 = pr8[97 + 4 * h];
  const short8 vv2 = pr8[98 + 4 * h], vv3 = pr8[99 + 4 * h];
  const float qscale = 0.20412414523193154f * 1.4426950408889634f * __expf(ls[h]);
  const float pos = (float)(t + posp[0]);
  const float invf[8] = {1.0f, 0.31622776601683794f, 0.1f, 0.031622776601683794f,
                         0.01f, 0.0031622776601683794f, 0.001f, 0.00031622776601683794f};
  short8 qv[4], kv[4];
  const short8 z8 = {0, 0, 0, 0, 0, 0, 0, 0};
  qv[3] = z8; kv[3] = z8;
#pragma unroll
  for (int i = 0; i < 8; ++i) {
    qv[0][i] = f2bf(bfs2f(qs8[i]) * qscale);
    kv[0][i] = ks8[i];
  }
#pragma unroll
  for (int i = 0; i < 8; ++i) {
    const float ang = pos * invf[i];
    float ss, cc;
    __sincosf(ang, &ss, &cc);
    const float x1q = bfs2f(qg1[i]), x2q = bfs2f(qg2[i]);
    const float x1k = bfs2f(kg1[i]), x2k = bfs2f(kg2[i]);
    qv[1][i] = f2bf((x1q * cc - x2q * ss) * qscale);
    qv[2][i] = f2bf((x1q * ss + x2q * cc) * qscale);
    kv[1][i] = f2bf(x1k * cc - x2k * ss);
    kv[2][i] = f2bf(x1k * ss + x2k * cc);
  }
  short8* qdst = reinterpret_cast<short8*>(Qp + ((size_t)h * TT + t) * 32);
  short8* kdst = reinterpret_cast<short8*>(Kp + ((size_t)h * TT + t) * 32);
#pragma unroll
  for (int p = 0; p < 4; ++p) { qdst[p] = qv[p]; kdst[p] = kv[p]; }
  __hip_bfloat16* vdst = Vt + (size_t)h * 32 * TT + t;
#pragma unroll
  for (int i = 0; i < 8; ++i) {
    *reinterpret_cast<short*>(vdst + (size_t)i * TT) = vv0[i];
    *reinterpret_cast<short*>(vdst + (size_t)(8 + i) * TT) = vv1[i];
    *reinterpret_cast<short*>(vdst + (size_t)(16 + i) * TT) = vv2[i];
    *reinterpret_cast<short*>(vdst + (size_t)(24 + i) * TT) = vv3[i];
  }
}

// ---------------- causal flash attention, BM=128 (2 Q-frags/wave) ----------------
// 512 blocks x 4 waves; block = (head, 128-row q-block), LPT (qb descending).
// Wave w owns rows [qb*128 + w*32, +32) as two 16-row fragments. K/V LDS tiles
// are read ONCE per wave and feed BOTH fragments -> LDS reads per q-row ~0.6x,
// barriers halve. LDS layouts = exact read order (ds_read = base + lane*16).
__global__ __launch_bounds__(256) void k_attn(const __hip_bfloat16* __restrict__ Qp,
    const __hip_bfloat16* __restrict__ Kp, const __hip_bfloat16* __restrict__ Vt,
    __hip_bfloat16* __restrict__ Ob) {
  __shared__ alignas(16) __hip_bfloat16 lK[2][64 * 32];   // 4KB each
  __shared__ alignas(16) __hip_bfloat16 lV[2][32 * 64];   // 4KB each
  __shared__ alignas(16) __hip_bfloat16 Plds[4][2][16][72];
  const int lin = blockIdx.x;           // 0..511
  const int xcd = lin & 7;
  const int idx = lin >> 3;             // 0..63
  const int h = xcd * 2 + (idx & 1);    // 2 heads per XCD
  const int qb = 31 - (idx >> 1);       // DESCENDING: big blocks first (LPT)
  const int nt = 2 * qb + 2;
  const int base = qb * 128;
  const int tid = threadIdx.x;
  const int lane = tid & 63, w = tid >> 6;
  const int g = lane >> 4, c = lane & 15;
  // staging source mapping (inverse of the LDS read permutation)
  const int krow = (tid >> 6) * 16 + (tid & 15);
  const int kcol = ((tid >> 4) & 3) * 8;
  const int vrow = ((tid >> 6) & 1) * 16 + (tid & 15);
  const int vcol = ((tid >> 7) & 1) * 32 + ((tid >> 4) & 3) * 8;
  const __hip_bfloat16* Kh = Kp + (size_t)h * TT * 32 + (size_t)krow * 32 + kcol;
  const __hip_bfloat16* Vh = Vt + (size_t)h * 32 * TT + (size_t)vrow * TT + vcol;
  const f32x4 zz = {0.f, 0.f, 0.f, 0.f};

  const int q0 = base + w * 32 + c;       // fragment 0 row
  const int q1 = q0 + 16;                 // fragment 1 row
  const short8 qf0 =
      *reinterpret_cast<const short8*>(Qp + ((size_t)h * TT + q0) * 32 + 8 * g);
  const short8 qf1 =
      *reinterpret_cast<const short8*>(Qp + ((size_t)h * TT + q1) * 32 + 8 * g);
  f32x4 o00 = zz, o01 = zz, o10 = zz, o11 = zz;
  float mst0 = -1e30f, ls0 = 0.f, mst1 = -1e30f, ls1 = 0.f;
  int cur = 0;
  __builtin_amdgcn_global_load_lds(
      (const __attribute__((address_space(1))) void*)Kh,
      (__attribute__((address_space(3))) void*)(lK[0] + tid * 8), 16, 0, 0);
  __builtin_amdgcn_global_load_lds(
      (const __attribute__((address_space(1))) void*)Vh,
      (__attribute__((address_space(3))) void*)(lV[0] + tid * 8), 16, 0, 0);

  for (int it = 0; it < nt; ++it) {
    __syncthreads();
    if (it + 1 < nt) {
      const int kv1 = (it + 1) * 64;
      __builtin_amdgcn_global_load_lds(
          (const __attribute__((address_space(1))) void*)(Kh + (size_t)kv1 * 32),
          (__attribute__((address_space(3))) void*)(lK[cur ^ 1] + tid * 8), 16, 0, 0);
      __builtin_amdgcn_global_load_lds(
          (const __attribute__((address_space(1))) void*)(Vh + kv1),
          (__attribute__((address_space(3))) void*)(lV[cur ^ 1] + tid * 8), 16, 0, 0);
    }
    const char* kb = (const char*)lK[cur];
    short8 kf[4];
#pragma unroll
    for (int ct = 0; ct < 4; ++ct)
      kf[ct] = *reinterpret_cast<const short8*>(kb + ct * 1024 + lane * 16);
    const char* vb = (const char*)lV[cur];
    const short8 v00 = *reinterpret_cast<const short8*>(vb + lane * 16);
    const short8 v10 = *reinterpret_cast<const short8*>(vb + 1024 + lane * 16);
    const short8 v01 = *reinterpret_cast<const short8*>(vb + 2048 + lane * 16);
    const short8 v11 = *reinterpret_cast<const short8*>(vb + 3072 + lane * 16);
    f32x4 s0[4], s1[4];
#pragma unroll
    for (int ct = 0; ct < 4; ++ct) {
      s0[ct] = __builtin_amdgcn_mfma_f32_16x16x32_bf16(kf[ct], qf0, zz, 0, 0, 0);
      s1[ct] = __builtin_amdgcn_mfma_f32_16x16x32_bf16(kf[ct], qf1, zz, 0, 0, 0);
    }
    if (it >= nt - 2) {  // last two tiles may cross the diagonal
      const int kv0 = it * 64;
#pragma unroll
      for (int ct = 0; ct < 4; ++ct)
#pragma unroll
        for (int j = 0; j < 4; ++j) {
          const int kvi = kv0 + ct * 16 + g * 4 + j;
          if (kvi > q0) s0[ct][j] = -1e30f;
          if (kvi > q1) s1[ct][j] = -1e30f;
        }
    }
    // ---- fragment 0 softmax ----
    {
      float m01 = fmaxf(fmaxf(s0[0][0], s0[0][1]), fmaxf(s0[0][2], s0[0][3]));
      float m23 = fmaxf(fmaxf(s0[1][0], s0[1][1]), fmaxf(s0[1][2], s0[1][3]));
      float m45 = fmaxf(fmaxf(s0[2][0], s0[2][1]), fmaxf(s0[2][2], s0[2][3]));
      float m67 = fmaxf(fmaxf(s0[3][0], s0[3][1]), fmaxf(s0[3][2], s0[3][3]));
      float pm_ = fmaxf(fmaxf(m01, m23), fmaxf(m45, m67));
      if (__any(pm_ > mst0 + 8.0f)) {
        float pm2 = fmaxf(pm_, __shfl_xor(pm_, 16, 64));
        pm2 = fmaxf(pm2, __shfl_xor(pm2, 32, 64));
        const float nm = fmaxf(mst0, pm2);
        const float alpha = exp2f(mst0 - nm);
        mst0 = nm;
        ls0 *= alpha;
#pragma unroll
        for (int j = 0; j < 4; ++j) { o00[j] *= alpha; o01[j] *= alpha; }
      }
      float ts = 0.f;
#pragma unroll
      for (int ct = 0; ct < 4; ++ct) {
#pragma unroll
        for (int j = 0; j < 4; ++j) s0[ct][j] = exp2f(s0[ct][j] - mst0);
        ts += (s0[ct][0] + s0[ct][1]) + (s0[ct][2] + s0[ct][3]);
      }
      ls0 += ts;
    }
    // ---- fragment 1 softmax ----
    {
      float m01 = fmaxf(fmaxf(s1[0][0], s1[0][1]), fmaxf(s1[0][2], s1[0][3]));
      float m23 = fmaxf(fmaxf(s1[1][0], s1[1][1]), fmaxf(s1[1][2], s1[1][3]));
      float m45 = fmaxf(fmaxf(s1[2][0], s1[2][1]), fmaxf(s1[2][2], s1[2][3]));
      float m67 = fmaxf(fmaxf(s1[3][0], s1[3][1]), fmaxf(s1[3][2], s1[3][3]));
      float pm_ = fmaxf(fmaxf(m01, m23), fmaxf(m45, m67));
      if (__any(pm_ > mst1 + 8.0f)) {
        float pm2 = fmaxf(pm_, __shfl_xor(pm_, 16, 64));
        pm2 = fmaxf(pm2, __shfl_xor(pm2, 32, 64));
        const float nm = fmaxf(mst1, pm2);
        const float alpha = exp2f(mst1 - nm);
        mst1 = nm;
        ls1 *= alpha;
#pragma unroll
        for (int j = 0; j < 4; ++j) { o10[j] *= alpha; o11[j] *= alpha; }
      }
      float ts = 0.f;
#pragma unroll
      for (int ct = 0; ct < 4; ++ct) {
#pragma unroll
        for (int j = 0; j < 4; ++j) s1[ct][j] = exp2f(s1[ct][j] - mst1);
        ts += (s1[ct][0] + s1[ct][1]) + (s1[ct][2] + s1[ct][3]);
      }
      ls1 += ts;
    }
    // P -> LDS (packed bf16 pairs), per-wave/frag private slices (2-way max: free)
#pragma unroll
    for (int ct = 0; ct < 4; ++ct) {
      float2 a01; a01.x = s0[ct][0]; a01.y = s0[ct][1];
      float2 a23; a23.x = s0[ct][2]; a23.y = s0[ct][3];
      __hip_bfloat162 b01 = __float22bfloat162_rn(a01);
      __hip_bfloat162 b23 = __float22bfloat162_rn(a23);
      *reinterpret_cast<__hip_bfloat162*>(&Plds[w][0][c][ct * 16 + g * 4]) = b01;
      *reinterpret_cast<__hip_bfloat162*>(&Plds[w][0][c][ct * 16 + g * 4 + 2]) = b23;
      float2 d01; d01.x = s1[ct][0]; d01.y = s1[ct][1];
      float2 d23; d23.x = s1[ct][2]; d23.y = s1[ct][3];
      __hip_bfloat162 e01 = __float22bfloat162_rn(d01);
      __hip_bfloat162 e23 = __float22bfloat162_rn(d23);
      *reinterpret_cast<__hip_bfloat162*>(&Plds[w][1][c][ct * 16 + g * 4]) = e01;
      *reinterpret_cast<__hip_bfloat162*>(&Plds[w][1][c][ct * 16 + g * 4 + 2]) = e23;
    }
    const short8 p00 = *reinterpret_cast<const short8*>(&Plds[w][0][c][8 * g]);
    const short8 p01 = *reinterpret_cast<const short8*>(&Plds[w][0][c][32 + 8 * g]);
    const short8 p10 = *reinterpret_cast<const short8*>(&Plds[w][1][c][8 * g]);
    const short8 p11 = *reinterpret_cast<const short8*>(&Plds[w][1][c][32 + 8 * g]);
    // O^T: C col = q-row = lane c; V fragments shared by both Q-frags
    o00 = __builtin_amdgcn_mfma_f32_16x16x32_bf16(v00, p00, o00, 0, 0, 0);
    o00 = __builtin_amdgcn_mfma_f32_16x16x32_bf16(v01, p01, o00, 0, 0, 0);
    o01 = __builtin_amdgcn_mfma_f32_16x16x32_bf16(v10, p00, o01, 0, 0, 0);
    o01 = __builtin_amdgcn_mfma_f32_16x16x32_bf16(v11, p01, o01, 0, 0, 0);
    o10 = __builtin_amdgcn_mfma_f32_16x16x32_bf16(v00, p10, o10, 0, 0, 0);
    o10 = __builtin_amdgcn_mfma_f32_16x16x32_bf16(v01, p11, o10, 0, 0, 0);
    o11 = __builtin_amdgcn_mfma_f32_16x16x32_bf16(v10, p10, o11, 0, 0, 0);
    o11 = __builtin_amdgcn_mfma_f32_16x16x32_bf16(v11, p11, o11, 0, 0, 0);
    cur ^= 1;
  }
  // final lsum reduces + writes (two rows per lane)
  ls0 += __shfl_xor(ls0, 16, 64);
  ls0 += __shfl_xor(ls0, 32, 64);
  ls1 += __shfl_xor(ls1, 16, 64);
  ls1 += __shfl_xor(ls1, 32, 64);
  const float inv0 = 1.0f / ls0, inv1 = 1.0f / ls1;
  __hip_bfloat16* dst0 = Ob + (size_t)q0 * DATTN + h * 32;
  __hip_bfloat16* dst1 = Ob + (size_t)q1 * DATTN + h * 32;
  short4v w00, w01, w10, w11;
#pragma unroll
  for (int j = 0; j < 4; ++j) {
    w00[j] = f2bf(o00[j] * inv0); w01[j] = f2bf(o01[j] * inv0);
    w10[j] = f2bf(o10[j] * inv1); w11[j] = f2bf(o11[j] * inv1);
  }
  *reinterpret_cast<short4v*>(dst0 + g * 4) = w00;
  *reinterpret_cast<short4v*>(dst0 + 16 + g * 4) = w01;
  *reinterpret_cast<short4v*>(dst1 + g * 4) = w10;
  *reinterpret_cast<short4v*>(dst1 + 16 + g * 4) = w11;
}

extern "C" void kernel_launch(void* const* d_in, const int* in_sizes, int n_in,
                              void* d_out, int out_size, void* d_ws, size_t ws_size,
                              hipStream_t stream) {
  const float* x   = (const float*)d_in[0];
  const float* qsw = (const float*)d_in[1];
  const float* ksw = (const float*)d_in[2];
  const float* qgw = (const float*)d_in[3];
  const float* kgw = (const float*)d_in[4];
  const float* vw  = (const float*)d_in[5];
  const float* ow  = (const float*)d_in[6];
  const float* ls  = (const float*)d_in[7];
  const int* posp  = (const int*)d_in[9];

  size_t off = 0;
  auto alloc = [&](size_t bytes) {
    char* p = (char*)d_ws + off;
    off += (bytes + 255) & ~(size_t)255;
    return (void*)p;
  };
  __hip_bfloat16* Xbf  = (__hip_bfloat16*)alloc((size_t)TT * DM * 2);
  __hip_bfloat16* Wcat = (__hip_bfloat16*)alloc((size_t)NPROJ * DM * 2);
  __hip_bfloat16* OW   = (__hip_bfloat16*)alloc((size_t)DM * DATTN * 2);
  __hip_bfloat16* proj = (__hip_bfloat16*)alloc((size_t)TT * NPROJ * 2);
  __hip_bfloat16* Qp   = (__hip_bfloat16*)alloc((size_t)NH * TT * 32 * 2);
  __hip_bfloat16* Kpk  = (__hip_bfloat16*)alloc((size_t)NH * TT * 32 * 2);
  __hip_bfloat16* Vt   = (__hip_bfloat16*)alloc((size_t)NH * 32 * TT * 2);
  __hip_bfloat16* Ob   = (__hip_bfloat16*)alloc((size_t)TT * DATTN * 2);

  k_prep<<<dim3(NB_X + NB_OW + NB_WC), 256, 0, stream>>>(x, ow, qsw, ksw, qgw, kgw, vw,
                                                         Xbf, OW, Wcat);
  k_gemm_bt<1><<<dim3(TT / 64, NPROJ / 128), 256, 0, stream>>>(Xbf, Wcat, (void*)proj,
                                                               TT, NPROJ, DM);
  k_rope_pack<<<dim3(TT * NH / 256), 256, 0, stream>>>(proj, ls, posp, Qp, Kpk, Vt);
  k_attn<<<dim3(512), 256, 0, stream>>>(Qp, Kpk, Vt, Ob);
  k_gemm_bt<0><<<dim3(TT / 64, DM / 128), 256, 0, stream>>>(Ob, OW, (void*)d_out,
                                                            TT, DM, DATTN);
}

// Round 17
// 122.927 us; speedup vs baseline: 1.2373x; 1.2373x over previous
//
#include <hip/hip_runtime.h>
#include <hip/hip_bf16.h>

typedef __attribute__((ext_vector_type(8))) short short8;
typedef __attribute__((ext_vector_type(4))) short short4v;
typedef __attribute__((ext_vector_type(4))) float f32x4;

#define TT 4096
#define DM 1024
#define NH 16
#define NPROJ 1280   // 128 qs + 128 ks + 256 qg + 256 kg + 512 v
#define DATTN 512

static __device__ __forceinline__ short f2bf(float f) {
  __hip_bfloat16 h = __float2bfloat16(f);
  return *reinterpret_cast<short*>(&h);
}
static __device__ __forceinline__ float bfs2f(short s) {
  __hip_bfloat16 h = *reinterpret_cast<__hip_bfloat16*>(&s);
  return __bfloat162float(h);
}
static __device__ __forceinline__ unsigned pk2(float a, float b) {
  float2 t; t.x = a; t.y = b;
  __hip_bfloat162 r = __float22bfloat162_rn(t);
  return *reinterpret_cast<unsigned*>(&r);
}

// ---------------- fused prep: x->bf16, ow->bf16, wcat concat (one launch) ----------------
#define NB_X   (TT * DM / 4 / 256)        // 4096 blocks
#define NB_OW  (DM * DATTN / 4 / 256)     // 512 blocks
#define NB_WC  (NPROJ * DM / 4 / 256)     // 1280 blocks
__global__ __launch_bounds__(256) void k_prep(const float* __restrict__ x,
    const float* __restrict__ ow, const float* __restrict__ qs, const float* __restrict__ ks,
    const float* __restrict__ qg, const float* __restrict__ kg, const float* __restrict__ vw,
    __hip_bfloat16* __restrict__ Xbf, __hip_bfloat16* __restrict__ OW,
    __hip_bfloat16* __restrict__ Wcat) {
  const int b = blockIdx.x;
  if (b < NB_X) {
    const int i = b * 256 + threadIdx.x;
    float4 v = reinterpret_cast<const float4*>(x)[i];
    short4v o;
    o[0] = f2bf(v.x); o[1] = f2bf(v.y); o[2] = f2bf(v.z); o[3] = f2bf(v.w);
    reinterpret_cast<short4v*>(Xbf)[i] = o;
  } else if (b < NB_X + NB_OW) {
    const int i = (b - NB_X) * 256 + threadIdx.x;
    float4 v = reinterpret_cast<const float4*>(ow)[i];
    short4v o;
    o[0] = f2bf(v.x); o[1] = f2bf(v.y); o[2] = f2bf(v.z); o[3] = f2bf(v.w);
    reinterpret_cast<short4v*>(OW)[i] = o;
  } else {
    const int i = (b - NB_X - NB_OW) * 256 + threadIdx.x;
    const int idx = i * 4;
    const int row = idx >> 10;
    const int col = idx & 1023;
    const float* src;
    if (row < 128)      src = qs + (size_t)row * DM;
    else if (row < 256) src = ks + (size_t)(row - 128) * DM;
    else if (row < 512) src = qg + (size_t)(row - 256) * DM;
    else if (row < 768) src = kg + (size_t)(row - 512) * DM;
    else                src = vw + (size_t)(row - 768) * DM;
    float4 v = *reinterpret_cast<const float4*>(src + col);
    short4v o;
    o[0] = f2bf(v.x); o[1] = f2bf(v.y); o[2] = f2bf(v.z); o[3] = f2bf(v.w);
    *reinterpret_cast<short4v*>(Wcat + idx) = o;
  }
}

// ---------------- bf16 GEMM, B^T layout, BM=64 BN=128 BK=32, double-buffered ----------
template<int OUT_BF16>
__global__ __launch_bounds__(256) void k_gemm_bt(const __hip_bfloat16* __restrict__ A,
    const __hip_bfloat16* __restrict__ B, void* __restrict__ Cv, int M, int N, int K) {
  __shared__ alignas(16) __hip_bfloat16 lA[2][64 * 32];
  __shared__ alignas(16) __hip_bfloat16 lB[2][128 * 32];
  const int tid = threadIdx.x;
  const int lane = tid & 63;
  const int wid = tid >> 6;
  const int m0 = blockIdx.x * 64, n0 = blockIdx.y * 128;
  const int wm = (wid >> 1) * 32, wn = (wid & 1) * 64;
  const int srow = tid >> 2;          // 0..63
  const int scol = (tid & 3) * 8;     // bf16 elements
  const int fr = lane & 15, fk = (lane >> 4) * 8;
  f32x4 acc[2][4];
  const f32x4 zz = {0.f, 0.f, 0.f, 0.f};
#pragma unroll
  for (int m = 0; m < 2; ++m)
#pragma unroll
    for (int n = 0; n < 4; ++n) acc[m][n] = zz;

  auto stage = [&](int kt, int buf) {
    const __hip_bfloat16* ga0 = A + (size_t)(m0 + srow) * K + kt + scol;
    const __hip_bfloat16* gb0 = B + (size_t)(n0 + srow) * K + kt + scol;
    const __hip_bfloat16* gb1 = B + (size_t)(n0 + 64 + srow) * K + kt + scol;
    __builtin_amdgcn_global_load_lds((const __attribute__((address_space(1))) void*)ga0,
        (__attribute__((address_space(3))) void*)(lA[buf] + srow * 32 + scol), 16, 0, 0);
    __builtin_amdgcn_global_load_lds((const __attribute__((address_space(1))) void*)gb0,
        (__attribute__((address_space(3))) void*)(lB[buf] + srow * 32 + scol), 16, 0, 0);
    __builtin_amdgcn_global_load_lds((const __attribute__((address_space(1))) void*)gb1,
        (__attribute__((address_space(3))) void*)(lB[buf] + (64 + srow) * 32 + scol), 16, 0, 0);
  };
  stage(0, 0);
  int buf = 0;
  for (int kt = 0; kt < K; kt += 32) {
    __syncthreads();   // staging of buf complete; prev reads of buf^1 done
    if (kt + 32 < K) stage(kt + 32, buf ^ 1);
    short8 af[2], bfr[4];
#pragma unroll
    for (int m = 0; m < 2; ++m)
      af[m] = *reinterpret_cast<const short8*>(lA[buf] + (wm + m * 16 + fr) * 32 + fk);
#pragma unroll
    for (int n = 0; n < 4; ++n)
      bfr[n] = *reinterpret_cast<const short8*>(lB[buf] + (wn + n * 16 + fr) * 32 + fk);
#pragma unroll
    for (int m = 0; m < 2; ++m)
#pragma unroll
      for (int n = 0; n < 4; ++n)
        acc[m][n] = __builtin_amdgcn_mfma_f32_16x16x32_bf16(af[m], bfr[n], acc[m][n], 0, 0, 0);
    buf ^= 1;
  }
  const int cr = (lane >> 4) * 4, cc = lane & 15;
#pragma unroll
  for (int m = 0; m < 2; ++m)
#pragma unroll
    for (int n = 0; n < 4; ++n)
#pragma unroll
      for (int j = 0; j < 4; ++j) {
        const int row = m0 + wm + m * 16 + cr + j;
        const int col = n0 + wn + n * 16 + cc;
        if (OUT_BF16)
          ((__hip_bfloat16*)Cv)[(size_t)row * N + col] = __float2bfloat16(acc[m][n][j]);
        else
          ((float*)Cv)[(size_t)row * N + col] = acc[m][n][j];
      }
}

// ---------------- RoPE + pack Q/K (H,T,32) and V^T (H,32,T), vectorized loads ----------
__global__ __launch_bounds__(256) void k_rope_pack(const __hip_bfloat16* __restrict__ proj,
    const float* __restrict__ ls, const int* __restrict__ posp,
    __hip_bfloat16* __restrict__ Qp, __hip_bfloat16* __restrict__ Kp,
    __hip_bfloat16* __restrict__ Vt) {
  const int gid = blockIdx.x * blockDim.x + threadIdx.x;  // T*NH, t fastest
  const int t = gid & (TT - 1);
  const int h = gid >> 12;
  const short8* pr8 = reinterpret_cast<const short8*>(proj + (size_t)t * NPROJ);
  const short8 qs8 = pr8[h];
  const short8 ks8 = pr8[16 + h];
  const short8 qg1 = pr8[32 + 2 * h], qg2 = pr8[33 + 2 * h];
  const short8 kg1 = pr8[64 + 2 * h], kg2 = pr8[65 + 2 * h];
  const short8 vv0 = pr8[96 + 4 * h], vv1 = pr8[97 + 4 * h];
  const short8 vv2 = pr8[98 + 4 * h], vv3 = pr8[99 + 4 * h];
  const float qscale = 0.20412414523193154f * 1.4426950408889634f * __expf(ls[h]);
  const float pos = (float)(t + posp[0]);
  const float invf[8] = {1.0f, 0.31622776601683794f, 0.1f, 0.031622776601683794f,
                         0.01f, 0.0031622776601683794f, 0.001f, 0.00031622776601683794f};
  short8 qv[4], kv[4];
  const short8 z8 = {0, 0, 0, 0, 0, 0, 0, 0};
  qv[3] = z8; kv[3] = z8;
#pragma unroll
  for (int i = 0; i < 8; ++i) {
    qv[0][i] = f2bf(bfs2f(qs8[i]) * qscale);
    kv[0][i] = ks8[i];
  }
#pragma unroll
  for (int i = 0; i < 8; ++i) {
    const float ang = pos * invf[i];
    float ss, cc;
    __sincosf(ang, &ss, &cc);
    const float x1q = bfs2f(qg1[i]), x2q = bfs2f(qg2[i]);
    const float x1k = bfs2f(kg1[i]), x2k = bfs2f(kg2[i]);
    qv[1][i] = f2bf((x1q * cc - x2q * ss) * qscale);
    qv[2][i] = f2bf((x1q * ss + x2q * cc) * qscale);
    kv[1][i] = f2bf(x1k * cc - x2k * ss);
    kv[2][i] = f2bf(x1k * ss + x2k * cc);
  }
  short8* qdst = reinterpret_cast<short8*>(Qp + ((size_t)h * TT + t) * 32);
  short8* kdst = reinterpret_cast<short8*>(Kp + ((size_t)h * TT + t) * 32);
#pragma unroll
  for (int p = 0; p < 4; ++p) { qdst[p] = qv[p]; kdst[p] = kv[p]; }
  __hip_bfloat16* vdst = Vt + (size_t)h * 32 * TT + t;
#pragma unroll
  for (int i = 0; i < 8; ++i) {
    *reinterpret_cast<short*>(vdst + (size_t)i * TT) = vv0[i];
    *reinterpret_cast<short*>(vdst + (size_t)(8 + i) * TT) = vv1[i];
    *reinterpret_cast<short*>(vdst + (size_t)(16 + i) * TT) = vv2[i];
    *reinterpret_cast<short*>(vdst + (size_t)(24 + i) * TT) = vv3[i];
  }
}

// ---------------- causal flash attention, 2x2 intra-block split ----------------
// 1024 blocks x 4 waves; block = (head, 64-row q-block), LPT (qb descending).
// Wave (qh,kh)=(w>>1,w&1): q-half [32qh,+32) x kv-half [32kh,+32) of each 64x64
// tile -> K/V LDS read duplication 4x -> 2x. P stays IN-REGISTER via the pi
// permutation (R13): PV B-frag = lane's own packed s; V^T read pi-permuted 8B.
// Per-wave (m,l,O) partials per q-frag; one LDS merge at end (kv-halves).
// Mask value is -INF so fully-masked fragments contribute exact zeros.
__global__ __launch_bounds__(256) void k_attn(const __hip_bfloat16* __restrict__ Qp,
    const __hip_bfloat16* __restrict__ Kp, const __hip_bfloat16* __restrict__ Vt,
    __hip_bfloat16* __restrict__ Ob) {
  __shared__ alignas(16) __hip_bfloat16 lK[2][64 * 32];    // 4KB each
  __shared__ alignas(16) __hip_bfloat16 lV[2][32 * 64];    // 4KB each
  __shared__ alignas(16) f32x4 Olds[4][2][2][4][16];       // [w][f][db][g][c] 16KB
  __shared__ float Mlds[4][2][16], Llds[4][2][16];
  const int lin = blockIdx.x;           // 0..1023
  const int xcd = lin & 7;
  const int idx = lin >> 3;             // 0..127
  const int h = xcd * 2 + (idx & 1);    // 2 heads per XCD
  const int qb = 63 - (idx >> 1);       // DESCENDING: big blocks first (LPT)
  const int nt = qb + 1;
  const int tid = threadIdx.x;
  const int lane = tid & 63, w = tid >> 6;
  const int qh = w >> 1, kh = w & 1;
  const int g = lane >> 4, c = lane & 15;
  const float NINF = -__builtin_inff();
  // staging source mapping (inverse of the LDS read permutation; same as R15)
  const int krow = (tid >> 6) * 16 + (tid & 15);
  const int kcol = ((tid >> 4) & 3) * 8;
  const int vrow = ((tid >> 6) & 1) * 16 + (tid & 15);
  const int vcol = ((tid >> 7) & 1) * 32 + ((tid >> 4) & 3) * 8;
  const __hip_bfloat16* Kh = Kp + (size_t)h * TT * 32 + (size_t)krow * 32 + kcol;
  const __hip_bfloat16* Vh = Vt + (size_t)h * 32 * TT + (size_t)vrow * TT + vcol;
  const f32x4 zz = {0.f, 0.f, 0.f, 0.f};
  // pi-permuted V base (R13) within this wave's kv-half / d-block segments
  const int vb0 = kh * 2048 + (g >> 1) * 256 + c * 16 + 8 * (g & 1);

  const int qbase = qb * 64 + 32 * qh;
  short8 qf[2];
#pragma unroll
  for (int f = 0; f < 2; ++f)
    qf[f] = *reinterpret_cast<const short8*>(Qp + ((size_t)h * TT + qbase + 16 * f + c) * 32 + 8 * g);
  f32x4 o[2][2];
  o[0][0] = zz; o[0][1] = zz; o[1][0] = zz; o[1][1] = zz;
  float mst[2] = {-1e30f, -1e30f};
  float lsum[2] = {0.f, 0.f};
  int cur = 0;
  __builtin_amdgcn_global_load_lds(
      (const __attribute__((address_space(1))) void*)Kh,
      (__attribute__((address_space(3))) void*)(lK[0] + tid * 8), 16, 0, 0);
  __builtin_amdgcn_global_load_lds(
      (const __attribute__((address_space(1))) void*)Vh,
      (__attribute__((address_space(3))) void*)(lV[0] + tid * 8), 16, 0, 0);

  for (int it = 0; it < nt; ++it) {
    __syncthreads();
    if (it + 1 < nt) {
      const int kv1 = (it + 1) * 64;
      __builtin_amdgcn_global_load_lds(
          (const __attribute__((address_space(1))) void*)(Kh + (size_t)kv1 * 32),
          (__attribute__((address_space(3))) void*)(lK[cur ^ 1] + tid * 8), 16, 0, 0);
      __builtin_amdgcn_global_load_lds(
          (const __attribute__((address_space(1))) void*)(Vh + kv1),
          (__attribute__((address_space(3))) void*)(lV[cur ^ 1] + tid * 8), 16, 0, 0);
    }
    // K fragments for this wave's kv-half: 2 x 16-kv blocks (conflict-free)
    const char* kb = (const char*)lK[cur];
    short8 kf[2];
#pragma unroll
    for (int ct = 0; ct < 2; ++ct)
      kf[ct] = *reinterpret_cast<const short8*>(kb + (2 * kh + ct) * 1024 + lane * 16);
    // V fragments, pi-permuted, per d-block (shared across both q-frags)
    const char* vb = (const char*)lV[cur];
    union U8 { unsigned u[4]; short8 v8; };
    U8 aV[2];
#pragma unroll
    for (int db = 0; db < 2; ++db) {
      *reinterpret_cast<uint2*>(&aV[db].u[0]) =
          *reinterpret_cast<const uint2*>(vb + vb0 + db * 1024);
      *reinterpret_cast<uint2*>(&aV[db].u[2]) =
          *reinterpret_cast<const uint2*>(vb + vb0 + db * 1024 + 512);
    }
    // QK^T: s[f][ct] -> P[q=c][kv = 32kh + 16ct + 4g + j]
    f32x4 s[2][2];
#pragma unroll
    for (int f = 0; f < 2; ++f)
#pragma unroll
      for (int ct = 0; ct < 2; ++ct)
        s[f][ct] = __builtin_amdgcn_mfma_f32_16x16x32_bf16(kf[ct], qf[f], zz, 0, 0, 0);
    if (it == nt - 1) {  // diagonal tile: mask kv > q (use -inf: exact zeros)
#pragma unroll
      for (int f = 0; f < 2; ++f)
#pragma unroll
        for (int ct = 0; ct < 2; ++ct)
#pragma unroll
          for (int j = 0; j < 4; ++j)
            if (32 * kh + 16 * ct + 4 * g + j > 32 * qh + 16 * f + c) s[f][ct][j] = NINF;
    }
#pragma unroll
    for (int f = 0; f < 2; ++f) {
      // in-lane max over this lane's 8 scores of frag f
      float a = fmaxf(fmaxf(s[f][0][0], s[f][0][1]), fmaxf(s[f][0][2], s[f][0][3]));
      float b = fmaxf(fmaxf(s[f][1][0], s[f][1][1]), fmaxf(s[f][1][2], s[f][1][3]));
      float pm_ = fmaxf(a, b);
      if (__any(pm_ > mst[f] + 8.0f)) {  // defer-max trigger
        float pm2 = fmaxf(pm_, __shfl_xor(pm_, 16, 64));
        pm2 = fmaxf(pm2, __shfl_xor(pm2, 32, 64));
        const float nm = fmaxf(mst[f], pm2);
        const float alpha = exp2f(mst[f] - nm);
        mst[f] = nm;
        lsum[f] *= alpha;
#pragma unroll
        for (int j = 0; j < 4; ++j) { o[f][0][j] *= alpha; o[f][1][j] *= alpha; }
      }
      float ts = 0.f;
#pragma unroll
      for (int ct = 0; ct < 2; ++ct) {
#pragma unroll
        for (int j = 0; j < 4; ++j) s[f][ct][j] = exp2f(s[f][ct][j] - mst[f]);
        ts += (s[f][ct][0] + s[f][ct][1]) + (s[f][ct][2] + s[f][ct][3]);
      }
      lsum[f] += ts;
      // pack P in-lane (pi permutation: B-frag = own values, no LDS)
      U8 pb;
      pb.u[0] = pk2(s[f][0][0], s[f][0][1]);
      pb.u[1] = pk2(s[f][0][2], s[f][0][3]);
      pb.u[2] = pk2(s[f][1][0], s[f][1][1]);
      pb.u[3] = pk2(s[f][1][2], s[f][1][3]);
      // O^T accumulate: C col = q-row = lane c
      o[f][0] = __builtin_amdgcn_mfma_f32_16x16x32_bf16(aV[0].v8, pb.v8, o[f][0], 0, 0, 0);
      o[f][1] = __builtin_amdgcn_mfma_f32_16x16x32_bf16(aV[1].v8, pb.v8, o[f][1], 0, 0, 0);
    }
    cur ^= 1;
  }
  // stash partials: O^T frag value j -> d = db*16 + 4g + j, q = qbase + 16f + c
#pragma unroll
  for (int f = 0; f < 2; ++f) {
    lsum[f] += __shfl_xor(lsum[f], 16, 64);
    lsum[f] += __shfl_xor(lsum[f], 32, 64);
#pragma unroll
    for (int db = 0; db < 2; ++db) Olds[w][f][db][g][c] = o[f][db];
    if (g == 0) { Mlds[w][f][c] = mst[f]; Llds[w][f][c] = lsum[f]; }
  }
  __syncthreads();
  // merge kv-halves: thread t -> q-local ql = t>>2, 8-d span dq = t&3
  {
    const int ql = tid >> 2, dq = tid & 3;
    const int mqh = ql >> 5, mf = (ql >> 4) & 1, mc = ql & 15;
    const int w0 = 2 * mqh, w1 = w0 + 1;
    const int db = dq >> 1, gp = (dq & 1) * 2;
    const float m0 = Mlds[w0][mf][mc], m1 = Mlds[w1][mf][mc];
    const float mm = fmaxf(m0, m1);
    const float e0 = exp2f(m0 - mm), e1 = exp2f(m1 - mm);
    const float inv = 1.0f / (Llds[w0][mf][mc] * e0 + Llds[w1][mf][mc] * e1);
    const f32x4 a0 = Olds[w0][mf][db][gp][mc], a1 = Olds[w0][mf][db][gp + 1][mc];
    const f32x4 b0 = Olds[w1][mf][db][gp][mc], b1 = Olds[w1][mf][db][gp + 1][mc];
    short8 ov;
#pragma unroll
    for (int j = 0; j < 4; ++j) {
      ov[j] = f2bf((a0[j] * e0 + b0[j] * e1) * inv);
      ov[4 + j] = f2bf((a1[j] * e0 + b1[j] * e1) * inv);
    }
    const int qrow = qb * 64 + ql;
    *reinterpret_cast<short8*>(Ob + (size_t)qrow * DATTN + h * 32 + db * 16 + gp * 4) = ov;
  }
}

extern "C" void kernel_launch(void* const* d_in, const int* in_sizes, int n_in,
                              void* d_out, int out_size, void* d_ws, size_t ws_size,
                              hipStream_t stream) {
  const float* x   = (const float*)d_in[0];
  const float* qsw = (const float*)d_in[1];
  const float* ksw = (const float*)d_in[2];
  const float* qgw = (const float*)d_in[3];
  const float* kgw = (const float*)d_in[4];
  const float* vw  = (const float*)d_in[5];
  const float* ow  = (const float*)d_in[6];
  const float* ls  = (const float*)d_in[7];
  const int* posp  = (const int*)d_in[9];

  size_t off = 0;
  auto alloc = [&](size_t bytes) {
    char* p = (char*)d_ws + off;
    off += (bytes + 255) & ~(size_t)255;
    return (void*)p;
  };
  __hip_bfloat16* Xbf  = (__hip_bfloat16*)alloc((size_t)TT * DM * 2);
  __hip_bfloat16* Wcat = (__hip_bfloat16*)alloc((size_t)NPROJ * DM * 2);
  __hip_bfloat16* OW   = (__hip_bfloat16*)alloc((size_t)DM * DATTN * 2);
  __hip_bfloat16* proj = (__hip_bfloat16*)alloc((size_t)TT * NPROJ * 2);
  __hip_bfloat16* Qp   = (__hip_bfloat16*)alloc((size_t)NH * TT * 32 * 2);
  __hip_bfloat16* Kpk  = (__hip_bfloat16*)alloc((size_t)NH * TT * 32 * 2);
  __hip_bfloat16* Vt   = (__hip_bfloat16*)alloc((size_t)NH * 32 * TT * 2);
  __hip_bfloat16* Ob   = (__hip_bfloat16*)alloc((size_t)TT * DATTN * 2);

  k_prep<<<dim3(NB_X + NB_OW + NB_WC), 256, 0, stream>>>(x, ow, qsw, ksw, qgw, kgw, vw,
                                                         Xbf, OW, Wcat);
  k_gemm_bt<1><<<dim3(TT / 64, NPROJ / 128), 256, 0, stream>>>(Xbf, Wcat, (void*)proj,
                                                               TT, NPROJ, DM);
  k_rope_pack<<<dim3(TT * NH / 256), 256, 0, stream>>>(proj, ls, posp, Qp, Kpk, Vt);
  k_attn<<<dim3(1024), 256, 0, stream>>>(Qp, Kpk, Vt, Ob);
  k_gemm_bt<0><<<dim3(TT / 64, DM / 128), 256, 0, stream>>>(Ob, OW, (void*)d_out,
                                                            TT, DM, DATTN);
}

// Round 18
// 119.664 us; speedup vs baseline: 1.2711x; 1.0273x over previous
//
#include <hip/hip_runtime.h>
#include <hip/hip_bf16.h>

typedef __attribute__((ext_vector_type(8))) short short8;
typedef __attribute__((ext_vector_type(4))) short short4v;
typedef __attribute__((ext_vector_type(4))) float f32x4;

#define TT 4096
#define DM 1024
#define NH 16
#define NPROJ 1280   // 128 qs + 128 ks + 256 qg + 256 kg + 512 v
#define DATTN 512

static __device__ __forceinline__ short f2bf(float f) {
  __hip_bfloat16 h = __float2bfloat16(f);
  return *reinterpret_cast<short*>(&h);
}
static __device__ __forceinline__ float bfs2f(short s) {
  __hip_bfloat16 h = *reinterpret_cast<__hip_bfloat16*>(&s);
  return __bfloat162float(h);
}

// ---------------- fused prep: x->bf16, ow->bf16, wcat concat (one launch) ----------------
#define NB_X   (TT * DM / 4 / 256)        // 4096 blocks
#define NB_OW  (DM * DATTN / 4 / 256)     // 512 blocks
#define NB_WC  (NPROJ * DM / 4 / 256)     // 1280 blocks
__global__ __launch_bounds__(256) void k_prep(const float* __restrict__ x,
    const float* __restrict__ ow, const float* __restrict__ qs, const float* __restrict__ ks,
    const float* __restrict__ qg, const float* __restrict__ kg, const float* __restrict__ vw,
    __hip_bfloat16* __restrict__ Xbf, __hip_bfloat16* __restrict__ OW,
    __hip_bfloat16* __restrict__ Wcat) {
  const int b = blockIdx.x;
  if (b < NB_X) {
    const int i = b * 256 + threadIdx.x;
    float4 v = reinterpret_cast<const float4*>(x)[i];
    short4v o;
    o[0] = f2bf(v.x); o[1] = f2bf(v.y); o[2] = f2bf(v.z); o[3] = f2bf(v.w);
    reinterpret_cast<short4v*>(Xbf)[i] = o;
  } else if (b < NB_X + NB_OW) {
    const int i = (b - NB_X) * 256 + threadIdx.x;
    float4 v = reinterpret_cast<const float4*>(ow)[i];
    short4v o;
    o[0] = f2bf(v.x); o[1] = f2bf(v.y); o[2] = f2bf(v.z); o[3] = f2bf(v.w);
    reinterpret_cast<short4v*>(OW)[i] = o;
  } else {
    const int i = (b - NB_X - NB_OW) * 256 + threadIdx.x;
    const int idx = i * 4;
    const int row = idx >> 10;
    const int col = idx & 1023;
    const float* src;
    if (row < 128)      src = qs + (size_t)row * DM;
    else if (row < 256) src = ks + (size_t)(row - 128) * DM;
    else if (row < 512) src = qg + (size_t)(row - 256) * DM;
    else if (row < 768) src = kg + (size_t)(row - 512) * DM;
    else                src = vw + (size_t)(row - 768) * DM;
    float4 v = *reinterpret_cast<const float4*>(src + col);
    short4v o;
    o[0] = f2bf(v.x); o[1] = f2bf(v.y); o[2] = f2bf(v.z); o[3] = f2bf(v.w);
    *reinterpret_cast<short4v*>(Wcat + idx) = o;
  }
}

// ---------------- bf16 GEMM, B^T layout, BM=64 BN=128 BK=32, double-buffered ----------
template<int OUT_BF16>
__global__ __launch_bounds__(256) void k_gemm_bt(const __hip_bfloat16* __restrict__ A,
    const __hip_bfloat16* __restrict__ B, void* __restrict__ Cv, int M, int N, int K) {
  __shared__ alignas(16) __hip_bfloat16 lA[2][64 * 32];
  __shared__ alignas(16) __hip_bfloat16 lB[2][128 * 32];
  const int tid = threadIdx.x;
  const int lane = tid & 63;
  const int wid = tid >> 6;
  const int m0 = blockIdx.x * 64, n0 = blockIdx.y * 128;
  const int wm = (wid >> 1) * 32, wn = (wid & 1) * 64;
  const int srow = tid >> 2;          // 0..63
  const int scol = (tid & 3) * 8;     // bf16 elements
  const int fr = lane & 15, fk = (lane >> 4) * 8;
  f32x4 acc[2][4];
  const f32x4 zz = {0.f, 0.f, 0.f, 0.f};
#pragma unroll
  for (int m = 0; m < 2; ++m)
#pragma unroll
    for (int n = 0; n < 4; ++n) acc[m][n] = zz;

  auto stage = [&](int kt, int buf) {
    const __hip_bfloat16* ga0 = A + (size_t)(m0 + srow) * K + kt + scol;
    const __hip_bfloat16* gb0 = B + (size_t)(n0 + srow) * K + kt + scol;
    const __hip_bfloat16* gb1 = B + (size_t)(n0 + 64 + srow) * K + kt + scol;
    __builtin_amdgcn_global_load_lds((const __attribute__((address_space(1))) void*)ga0,
        (__attribute__((address_space(3))) void*)(lA[buf] + srow * 32 + scol), 16, 0, 0);
    __builtin_amdgcn_global_load_lds((const __attribute__((address_space(1))) void*)gb0,
        (__attribute__((address_space(3))) void*)(lB[buf] + srow * 32 + scol), 16, 0, 0);
    __builtin_amdgcn_global_load_lds((const __attribute__((address_space(1))) void*)gb1,
        (__attribute__((address_space(3))) void*)(lB[buf] + (64 + srow) * 32 + scol), 16, 0, 0);
  };
  stage(0, 0);
  int buf = 0;
  for (int kt = 0; kt < K; kt += 32) {
    __syncthreads();   // staging of buf complete; prev reads of buf^1 done
    if (kt + 32 < K) stage(kt + 32, buf ^ 1);
    short8 af[2], bfr[4];
#pragma unroll
    for (int m = 0; m < 2; ++m)
      af[m] = *reinterpret_cast<const short8*>(lA[buf] + (wm + m * 16 + fr) * 32 + fk);
#pragma unroll
    for (int n = 0; n < 4; ++n)
      bfr[n] = *reinterpret_cast<const short8*>(lB[buf] + (wn + n * 16 + fr) * 32 + fk);
#pragma unroll
    for (int m = 0; m < 2; ++m)
#pragma unroll
      for (int n = 0; n < 4; ++n)
        acc[m][n] = __builtin_amdgcn_mfma_f32_16x16x32_bf16(af[m], bfr[n], acc[m][n], 0, 0, 0);
    buf ^= 1;
  }
  const int cr = (lane >> 4) * 4, cc = lane & 15;
#pragma unroll
  for (int m = 0; m < 2; ++m)
#pragma unroll
    for (int n = 0; n < 4; ++n)
#pragma unroll
      for (int j = 0; j < 4; ++j) {
        const int row = m0 + wm + m * 16 + cr + j;
        const int col = n0 + wn + n * 16 + cc;
        if (OUT_BF16)
          ((__hip_bfloat16*)Cv)[(size_t)row * N + col] = __float2bfloat16(acc[m][n][j]);
        else
          ((float*)Cv)[(size_t)row * N + col] = acc[m][n][j];
      }
}

// ---------------- RoPE + pack Q/K (H,T,32) and V^T (H,32,T), vectorized loads ----------
__global__ __launch_bounds__(256) void k_rope_pack(const __hip_bfloat16* __restrict__ proj,
    const float* __restrict__ ls, const int* __restrict__ posp,
    __hip_bfloat16* __restrict__ Qp, __hip_bfloat16* __restrict__ Kp,
    __hip_bfloat16* __restrict__ Vt) {
  const int gid = blockIdx.x * blockDim.x + threadIdx.x;  // T*NH, t fastest
  const int t = gid & (TT - 1);
  const int h = gid >> 12;
  const short8* pr8 = reinterpret_cast<const short8*>(proj + (size_t)t * NPROJ);
  const short8 qs8 = pr8[h];
  const short8 ks8 = pr8[16 + h];
  const short8 qg1 = pr8[32 + 2 * h], qg2 = pr8[33 + 2 * h];
  const short8 kg1 = pr8[64 + 2 * h], kg2 = pr8[65 + 2 * h];
  const short8 vv0 = pr8[96 + 4 * h], vv1 = pr8[97 + 4 * h];
  const short8 vv2 = pr8[98 + 4 * h], vv3 = pr8[99 + 4 * h];
  const float qscale = 0.20412414523193154f * 1.4426950408889634f * __expf(ls[h]);
  const float pos = (float)(t + posp[0]);
  const float invf[8] = {1.0f, 0.31622776601683794f, 0.1f, 0.031622776601683794f,
                         0.01f, 0.0031622776601683794f, 0.001f, 0.00031622776601683794f};
  short8 qv[4], kv[4];
  const short8 z8 = {0, 0, 0, 0, 0, 0, 0, 0};
  qv[3] = z8; kv[3] = z8;
#pragma unroll
  for (int i = 0; i < 8; ++i) {
    qv[0][i] = f2bf(bfs2f(qs8[i]) * qscale);
    kv[0][i] = ks8[i];
  }
#pragma unroll
  for (int i = 0; i < 8; ++i) {
    const float ang = pos * invf[i];
    float ss, cc;
    __sincosf(ang, &ss, &cc);
    const float x1q = bfs2f(qg1[i]), x2q = bfs2f(qg2[i]);
    const float x1k = bfs2f(kg1[i]), x2k = bfs2f(kg2[i]);
    qv[1][i] = f2bf((x1q * cc - x2q * ss) * qscale);
    qv[2][i] = f2bf((x1q * ss + x2q * cc) * qscale);
    kv[1][i] = f2bf(x1k * cc - x2k * ss);
    kv[2][i] = f2bf(x1k * ss + x2k * cc);
  }
  short8* qdst = reinterpret_cast<short8*>(Qp + ((size_t)h * TT + t) * 32);
  short8* kdst = reinterpret_cast<short8*>(Kp + ((size_t)h * TT + t) * 32);
#pragma unroll
  for (int p = 0; p < 4; ++p) { qdst[p] = qv[p]; kdst[p] = kv[p]; }
  __hip_bfloat16* vdst = Vt + (size_t)h * 32 * TT + t;
#pragma unroll
  for (int i = 0; i < 8; ++i) {
    *reinterpret_cast<short*>(vdst + (size_t)i * TT) = vv0[i];
    *reinterpret_cast<short*>(vdst + (size_t)(8 + i) * TT) = vv1[i];
    *reinterpret_cast<short*>(vdst + (size_t)(16 + i) * TT) = vv2[i];
    *reinterpret_cast<short*>(vdst + (size_t)(24 + i) * TT) = vv3[i];
  }
}

// ---------------- causal flash attention (R11: LDS K/V, LPT, 4 blocks/CU) -------------
// 1024 blocks x 4 waves; block = one (head, 64-row q-block). qb DESCENDS with
// blockIdx (LPT). LDS layouts = exact read order (ds_read = base + lane*16,
// conflict-free); staging inverse-permutes the GLOBAL source per lane.
__global__ __launch_bounds__(256) void k_attn(const __hip_bfloat16* __restrict__ Qp,
    const __hip_bfloat16* __restrict__ Kp, const __hip_bfloat16* __restrict__ Vt,
    __hip_bfloat16* __restrict__ Ob) {
  __shared__ alignas(16) __hip_bfloat16 lK[2][64 * 32];   // 4KB each
  __shared__ alignas(16) __hip_bfloat16 lV[2][32 * 64];   // 4KB each
  __shared__ alignas(16) __hip_bfloat16 Plds[4][16][72];
  const int lin = blockIdx.x;           // 0..1023
  const int xcd = lin & 7;
  const int idx = lin >> 3;             // 0..127
  const int h = xcd * 2 + (idx & 1);    // 2 heads per XCD
  const int qb = 63 - (idx >> 1);       // DESCENDING: big blocks first (LPT)
  const int nt = qb + 1;
  const int tid = threadIdx.x;
  const int lane = tid & 63, w = tid >> 6;
  const int g = lane >> 4, c = lane & 15;
  // staging source mapping (inverse of the LDS read permutation)
  const int krow = (tid >> 6) * 16 + (tid & 15);
  const int kcol = ((tid >> 4) & 3) * 8;
  const int vrow = ((tid >> 6) & 1) * 16 + (tid & 15);
  const int vcol = ((tid >> 7) & 1) * 32 + ((tid >> 4) & 3) * 8;
  const __hip_bfloat16* Kh = Kp + (size_t)h * TT * 32 + (size_t)krow * 32 + kcol;
  const __hip_bfloat16* Vh = Vt + (size_t)h * 32 * TT + (size_t)vrow * TT + vcol;
  const f32x4 zz = {0.f, 0.f, 0.f, 0.f};

  const int qrow = qb * 64 + w * 16 + c;
  const short8 qf =
      *reinterpret_cast<const short8*>(Qp + ((size_t)h * TT + qrow) * 32 + 8 * g);
  f32x4 o0 = zz, o1 = zz;
  float mst = -1e30f, lsum = 0.f;
  int cur = 0;
  __builtin_amdgcn_global_load_lds(
      (const __attribute__((address_space(1))) void*)Kh,
      (__attribute__((address_space(3))) void*)(lK[0] + tid * 8), 16, 0, 0);
  __builtin_amdgcn_global_load_lds(
      (const __attribute__((address_space(1))) void*)Vh,
      (__attribute__((address_space(3))) void*)(lV[0] + tid * 8), 16, 0, 0);

  for (int it = 0; it < nt; ++it) {
    __syncthreads();  // buf[cur] staged + all waves done with buf[cur^1]
    if (it + 1 < nt) {
      const int kv1 = (it + 1) * 64;
      __builtin_amdgcn_global_load_lds(
          (const __attribute__((address_space(1))) void*)(Kh + (size_t)kv1 * 32),
          (__attribute__((address_space(3))) void*)(lK[cur ^ 1] + tid * 8), 16, 0, 0);
      __builtin_amdgcn_global_load_lds(
          (const __attribute__((address_space(1))) void*)(Vh + kv1),
          (__attribute__((address_space(3))) void*)(lV[cur ^ 1] + tid * 8), 16, 0, 0);
    }
    // K fragments: addr = base + lane*16 (conflict-free)
    const char* kb = (const char*)lK[cur];
    short8 kf[4];
#pragma unroll
    for (int ct = 0; ct < 4; ++ct)
      kf[ct] = *reinterpret_cast<const short8*>(kb + ct * 1024 + lane * 16);
    // V fragments: addr = base + lane*16 (conflict-free)
    const char* vb = (const char*)lV[cur];
    const short8 v00 = *reinterpret_cast<const short8*>(vb + lane * 16);
    const short8 v10 = *reinterpret_cast<const short8*>(vb + 1024 + lane * 16);
    const short8 v01 = *reinterpret_cast<const short8*>(vb + 2048 + lane * 16);
    const short8 v11 = *reinterpret_cast<const short8*>(vb + 3072 + lane * 16);
    f32x4 s[4];
#pragma unroll
    for (int ct = 0; ct < 4; ++ct)
      s[ct] = __builtin_amdgcn_mfma_f32_16x16x32_bf16(kf[ct], qf, zz, 0, 0, 0);  // swapped
    if (it == nt - 1) {  // diagonal tile: mask k > q
#pragma unroll
      for (int ct = 0; ct < 4; ++ct)
#pragma unroll
        for (int j = 0; j < 4; ++j)
          if (ct * 16 + g * 4 + j > w * 16 + c) s[ct][j] = -1e30f;
    }
    // in-lane max over 16 scores
    float m01 = fmaxf(fmaxf(s[0][0], s[0][1]), fmaxf(s[0][2], s[0][3]));
    float m23 = fmaxf(fmaxf(s[1][0], s[1][1]), fmaxf(s[1][2], s[1][3]));
    float m45 = fmaxf(fmaxf(s[2][0], s[2][1]), fmaxf(s[2][2], s[2][3]));
    float m67 = fmaxf(fmaxf(s[3][0], s[3][1]), fmaxf(s[3][2], s[3][3]));
    float pm_ = fmaxf(fmaxf(m01, m23), fmaxf(m45, m67));
    if (__any(pm_ > mst + 8.0f)) {  // defer-max
      float pm2 = fmaxf(pm_, __shfl_xor(pm_, 16, 64));
      pm2 = fmaxf(pm2, __shfl_xor(pm2, 32, 64));
      const float nm = fmaxf(mst, pm2);
      const float alpha = exp2f(mst - nm);
      mst = nm;
      lsum *= alpha;
#pragma unroll
      for (int j = 0; j < 4; ++j) { o0[j] *= alpha; o1[j] *= alpha; }
    }
    float ts = 0.f;
#pragma unroll
    for (int ct = 0; ct < 4; ++ct) {
#pragma unroll
      for (int j = 0; j < 4; ++j) s[ct][j] = exp2f(s[ct][j] - mst);
      ts += (s[ct][0] + s[ct][1]) + (s[ct][2] + s[ct][3]);
    }
    lsum += ts;
    // P -> LDS (packed bf16 pairs), per-wave private slice (2-way max: free)
#pragma unroll
    for (int ct = 0; ct < 4; ++ct) {
      float2 p01; p01.x = s[ct][0]; p01.y = s[ct][1];
      float2 p23; p23.x = s[ct][2]; p23.y = s[ct][3];
      __hip_bfloat162 b01 = __float22bfloat162_rn(p01);
      __hip_bfloat162 b23 = __float22bfloat162_rn(p23);
      *reinterpret_cast<__hip_bfloat162*>(&Plds[w][c][ct * 16 + g * 4]) = b01;
      *reinterpret_cast<__hip_bfloat162*>(&Plds[w][c][ct * 16 + g * 4 + 2]) = b23;
    }
    const short8 pf0 = *reinterpret_cast<const short8*>(&Plds[w][c][8 * g]);
    const short8 pf1 = *reinterpret_cast<const short8*>(&Plds[w][c][32 + 8 * g]);
    // O^T: C col = q-row = lane c
    o0 = __builtin_amdgcn_mfma_f32_16x16x32_bf16(v00, pf0, o0, 0, 0, 0);
    o0 = __builtin_amdgcn_mfma_f32_16x16x32_bf16(v01, pf1, o0, 0, 0, 0);
    o1 = __builtin_amdgcn_mfma_f32_16x16x32_bf16(v10, pf0, o1, 0, 0, 0);
    o1 = __builtin_amdgcn_mfma_f32_16x16x32_bf16(v11, pf1, o1, 0, 0, 0);
    cur ^= 1;
  }
  // final lsum reduce across g-lanes of row c; write Ob
  lsum += __shfl_xor(lsum, 16, 64);
  lsum += __shfl_xor(lsum, 32, 64);
  const float inv = 1.0f / lsum;
  __hip_bfloat16* dst = Ob + (size_t)qrow * DATTN + h * 32;
  short4v w0, w1;
#pragma unroll
  for (int j = 0; j < 4; ++j) { w0[j] = f2bf(o0[j] * inv); w1[j] = f2bf(o1[j] * inv); }
  *reinterpret_cast<short4v*>(dst + g * 4) = w0;
  *reinterpret_cast<short4v*>(dst + 16 + g * 4) = w1;
}

extern "C" void kernel_launch(void* const* d_in, const int* in_sizes, int n_in,
                              void* d_out, int out_size, void* d_ws, size_t ws_size,
                              hipStream_t stream) {
  const float* x   = (const float*)d_in[0];
  const float* qsw = (const float*)d_in[1];
  const float* ksw = (const float*)d_in[2];
  const float* qgw = (const float*)d_in[3];
  const float* kgw = (const float*)d_in[4];
  const float* vw  = (const float*)d_in[5];
  const float* ow  = (const float*)d_in[6];
  const float* ls  = (const float*)d_in[7];
  const int* posp  = (const int*)d_in[9];

  size_t off = 0;
  auto alloc = [&](size_t bytes) {
    char* p = (char*)d_ws + off;
    off += (bytes + 255) & ~(size_t)255;
    return (void*)p;
  };
  __hip_bfloat16* Xbf  = (__hip_bfloat16*)alloc((size_t)TT * DM * 2);
  __hip_bfloat16* Wcat = (__hip_bfloat16*)alloc((size_t)NPROJ * DM * 2);
  __hip_bfloat16* OW   = (__hip_bfloat16*)alloc((size_t)DM * DATTN * 2);
  __hip_bfloat16* proj = (__hip_bfloat16*)alloc((size_t)TT * NPROJ * 2);
  __hip_bfloat16* Qp   = (__hip_bfloat16*)alloc((size_t)NH * TT * 32 * 2);
  __hip_bfloat16* Kpk  = (__hip_bfloat16*)alloc((size_t)NH * TT * 32 * 2);
  __hip_bfloat16* Vt   = (__hip_bfloat16*)alloc((size_t)NH * 32 * TT * 2);
  __hip_bfloat16* Ob   = (__hip_bfloat16*)alloc((size_t)TT * DATTN * 2);

  k_prep<<<dim3(NB_X + NB_OW + NB_WC), 256, 0, stream>>>(x, ow, qsw, ksw, qgw, kgw, vw,
                                                         Xbf, OW, Wcat);
  k_gemm_bt<1><<<dim3(TT / 64, NPROJ / 128), 256, 0, stream>>>(Xbf, Wcat, (void*)proj,
                                                               TT, NPROJ, DM);
  k_rope_pack<<<dim3(TT * NH / 256), 256, 0, stream>>>(proj, ls, posp, Qp, Kpk, Vt);
  k_attn<<<dim3(1024), 256, 0, stream>>>(Qp, Kpk, Vt, Ob);
  k_gemm_bt<0><<<dim3(TT / 64, DM / 128), 256, 0, stream>>>(Ob, OW, (void*)d_out,
                                                            TT, DM, DATTN);
}

// Round 19
// 118.662 us; speedup vs baseline: 1.2818x; 1.0084x over previous
//
#include <hip/hip_runtime.h>
#include <hip/hip_bf16.h>

typedef __attribute__((ext_vector_type(8))) short short8;
typedef __attribute__((ext_vector_type(4))) short short4v;
typedef __attribute__((ext_vector_type(4))) float f32x4;

#define TT 4096
#define DM 1024
#define NH 16
#define NPROJ 1280   // 128 qs + 128 ks + 256 qg + 256 kg + 512 v
#define DATTN 512

static __device__ __forceinline__ short f2bf(float f) {
  __hip_bfloat16 h = __float2bfloat16(f);
  return *reinterpret_cast<short*>(&h);
}
static __device__ __forceinline__ float bfs2f(short s) {
  __hip_bfloat16 h = *reinterpret_cast<__hip_bfloat16*>(&s);
  return __bfloat162float(h);
}

// ---------------- fused prep: x->bf16, ow->bf16, wcat concat (one launch) ----------------
#define NB_X   (TT * DM / 4 / 256)        // 4096 blocks
#define NB_OW  (DM * DATTN / 4 / 256)     // 512 blocks
#define NB_WC  (NPROJ * DM / 4 / 256)     // 1280 blocks
__global__ __launch_bounds__(256) void k_prep(const float* __restrict__ x,
    const float* __restrict__ ow, const float* __restrict__ qs, const float* __restrict__ ks,
    const float* __restrict__ qg, const float* __restrict__ kg, const float* __restrict__ vw,
    __hip_bfloat16* __restrict__ Xbf, __hip_bfloat16* __restrict__ OW,
    __hip_bfloat16* __restrict__ Wcat) {
  const int b = blockIdx.x;
  if (b < NB_X) {
    const int i = b * 256 + threadIdx.x;
    float4 v = reinterpret_cast<const float4*>(x)[i];
    short4v o;
    o[0] = f2bf(v.x); o[1] = f2bf(v.y); o[2] = f2bf(v.z); o[3] = f2bf(v.w);
    reinterpret_cast<short4v*>(Xbf)[i] = o;
  } else if (b < NB_X + NB_OW) {
    const int i = (b - NB_X) * 256 + threadIdx.x;
    float4 v = reinterpret_cast<const float4*>(ow)[i];
    short4v o;
    o[0] = f2bf(v.x); o[1] = f2bf(v.y); o[2] = f2bf(v.z); o[3] = f2bf(v.w);
    reinterpret_cast<short4v*>(OW)[i] = o;
  } else {
    const int i = (b - NB_X - NB_OW) * 256 + threadIdx.x;
    const int idx = i * 4;
    const int row = idx >> 10;
    const int col = idx & 1023;
    const float* src;
    if (row < 128)      src = qs + (size_t)row * DM;
    else if (row < 256) src = ks + (size_t)(row - 128) * DM;
    else if (row < 512) src = qg + (size_t)(row - 256) * DM;
    else if (row < 768) src = kg + (size_t)(row - 512) * DM;
    else                src = vw + (size_t)(row - 768) * DM;
    float4 v = *reinterpret_cast<const float4*>(src + col);
    short4v o;
    o[0] = f2bf(v.x); o[1] = f2bf(v.y); o[2] = f2bf(v.z); o[3] = f2bf(v.w);
    *reinterpret_cast<short4v*>(Wcat + idx) = o;
  }
}

// ---------------- bf16 GEMM, B^T layout, BM=64 BN=128 BK=64, double-buffered ----------
// BK=64 stored as TWO [64][32]-shaped panels so fragment reads keep the proven
// [row][32] stride (conflict behavior identical to BK=32); one barrier per 64-K
// (half the barrier/stage rounds, 16 MFMA per barrier). 48KB LDS -> 3 blocks/CU.
template<int OUT_BF16>
__global__ __launch_bounds__(256) void k_gemm_bt(const __hip_bfloat16* __restrict__ A,
    const __hip_bfloat16* __restrict__ B, void* __restrict__ Cv, int M, int N, int K) {
  __shared__ alignas(16) __hip_bfloat16 lA[2][2][64 * 32];    // [buf][kk]
  __shared__ alignas(16) __hip_bfloat16 lB[2][2][128 * 32];   // [buf][kk]
  const int tid = threadIdx.x;
  const int lane = tid & 63;
  const int wid = tid >> 6;
  const int m0 = blockIdx.x * 64, n0 = blockIdx.y * 128;
  const int wm = (wid >> 1) * 32, wn = (wid & 1) * 64;
  const int srow = tid >> 2;          // 0..63
  const int scol = (tid & 3) * 8;     // bf16 elements within a 32-col panel
  const int fr = lane & 15, fk = (lane >> 4) * 8;
  f32x4 acc[2][4];
  const f32x4 zz = {0.f, 0.f, 0.f, 0.f};
#pragma unroll
  for (int m = 0; m < 2; ++m)
#pragma unroll
    for (int n = 0; n < 4; ++n) acc[m][n] = zz;

  auto stage = [&](int kt, int buf) {
#pragma unroll
    for (int kk = 0; kk < 2; ++kk) {
      const int kcol = kt + kk * 32 + scol;
      const __hip_bfloat16* ga0 = A + (size_t)(m0 + srow) * K + kcol;
      const __hip_bfloat16* gb0 = B + (size_t)(n0 + srow) * K + kcol;
      const __hip_bfloat16* gb1 = B + (size_t)(n0 + 64 + srow) * K + kcol;
      __builtin_amdgcn_global_load_lds((const __attribute__((address_space(1))) void*)ga0,
          (__attribute__((address_space(3))) void*)(lA[buf][kk] + srow * 32 + scol), 16, 0, 0);
      __builtin_amdgcn_global_load_lds((const __attribute__((address_space(1))) void*)gb0,
          (__attribute__((address_space(3))) void*)(lB[buf][kk] + srow * 32 + scol), 16, 0, 0);
      __builtin_amdgcn_global_load_lds((const __attribute__((address_space(1))) void*)gb1,
          (__attribute__((address_space(3))) void*)(lB[buf][kk] + (64 + srow) * 32 + scol), 16, 0, 0);
    }
  };
  stage(0, 0);
  int buf = 0;
  for (int kt = 0; kt < K; kt += 64) {
    __syncthreads();   // staging of buf complete; prev reads of buf^1 done
    if (kt + 64 < K) stage(kt + 64, buf ^ 1);
#pragma unroll
    for (int kk = 0; kk < 2; ++kk) {
      short8 af[2], bfr[4];
#pragma unroll
      for (int m = 0; m < 2; ++m)
        af[m] = *reinterpret_cast<const short8*>(lA[buf][kk] + (wm + m * 16 + fr) * 32 + fk);
#pragma unroll
      for (int n = 0; n < 4; ++n)
        bfr[n] = *reinterpret_cast<const short8*>(lB[buf][kk] + (wn + n * 16 + fr) * 32 + fk);
#pragma unroll
      for (int m = 0; m < 2; ++m)
#pragma unroll
        for (int n = 0; n < 4; ++n)
          acc[m][n] = __builtin_amdgcn_mfma_f32_16x16x32_bf16(af[m], bfr[n], acc[m][n], 0, 0, 0);
    }
    buf ^= 1;
  }
  const int cr = (lane >> 4) * 4, cc = lane & 15;
#pragma unroll
  for (int m = 0; m < 2; ++m)
#pragma unroll
    for (int n = 0; n < 4; ++n)
#pragma unroll
      for (int j = 0; j < 4; ++j) {
        const int row = m0 + wm + m * 16 + cr + j;
        const int col = n0 + wn + n * 16 + cc;
        if (OUT_BF16)
          ((__hip_bfloat16*)Cv)[(size_t)row * N + col] = __float2bfloat16(acc[m][n][j]);
        else
          ((float*)Cv)[(size_t)row * N + col] = acc[m][n][j];
      }
}

// ---------------- RoPE + pack Q/K (H,T,32) and V^T (H,32,T), vectorized loads ----------
__global__ __launch_bounds__(256) void k_rope_pack(const __hip_bfloat16* __restrict__ proj,
    const float* __restrict__ ls, const int* __restrict__ posp,
    __hip_bfloat16* __restrict__ Qp, __hip_bfloat16* __restrict__ Kp,
    __hip_bfloat16* __restrict__ Vt) {
  const int gid = blockIdx.x * blockDim.x + threadIdx.x;  // T*NH, t fastest
  const int t = gid & (TT - 1);
  const int h = gid >> 12;
  const short8* pr8 = reinterpret_cast<const short8*>(proj + (size_t)t * NPROJ);
  const short8 qs8 = pr8[h];
  const short8 ks8 = pr8[16 + h];
  const short8 qg1 = pr8[32 + 2 * h], qg2 = pr8[33 + 2 * h];
  const short8 kg1 = pr8[64 + 2 * h], kg2 = pr8[65 + 2 * h];
  const short8 vv0 = pr8[96 + 4 * h], vv1 = pr8[97 + 4 * h];
  const short8 vv2 = pr8[98 + 4 * h], vv3 = pr8[99 + 4 * h];
  const float qscale = 0.20412414523193154f * 1.4426950408889634f * __expf(ls[h]);
  const float pos = (float)(t + posp[0]);
  const float invf[8] = {1.0f, 0.31622776601683794f, 0.1f, 0.031622776601683794f,
                         0.01f, 0.0031622776601683794f, 0.001f, 0.00031622776601683794f};
  short8 qv[4], kv[4];
  const short8 z8 = {0, 0, 0, 0, 0, 0, 0, 0};
  qv[3] = z8; kv[3] = z8;
#pragma unroll
  for (int i = 0; i < 8; ++i) {
    qv[0][i] = f2bf(bfs2f(qs8[i]) * qscale);
    kv[0][i] = ks8[i];
  }
#pragma unroll
  for (int i = 0; i < 8; ++i) {
    const float ang = pos * invf[i];
    float ss, cc;
    __sincosf(ang, &ss, &cc);
    const float x1q = bfs2f(qg1[i]), x2q = bfs2f(qg2[i]);
    const float x1k = bfs2f(kg1[i]), x2k = bfs2f(kg2[i]);
    qv[1][i] = f2bf((x1q * cc - x2q * ss) * qscale);
    qv[2][i] = f2bf((x1q * ss + x2q * cc) * qscale);
    kv[1][i] = f2bf(x1k * cc - x2k * ss);
    kv[2][i] = f2bf(x1k * ss + x2k * cc);
  }
  short8* qdst = reinterpret_cast<short8*>(Qp + ((size_t)h * TT + t) * 32);
  short8* kdst = reinterpret_cast<short8*>(Kp + ((size_t)h * TT + t) * 32);
#pragma unroll
  for (int p = 0; p < 4; ++p) { qdst[p] = qv[p]; kdst[p] = kv[p]; }
  __hip_bfloat16* vdst = Vt + (size_t)h * 32 * TT + t;
#pragma unroll
  for (int i = 0; i < 8; ++i) {
    *reinterpret_cast<short*>(vdst + (size_t)i * TT) = vv0[i];
    *reinterpret_cast<short*>(vdst + (size_t)(8 + i) * TT) = vv1[i];
    *reinterpret_cast<short*>(vdst + (size_t)(16 + i) * TT) = vv2[i];
    *reinterpret_cast<short*>(vdst + (size_t)(24 + i) * TT) = vv3[i];
  }
}

// ---------------- causal flash attention (R11: LDS K/V, LPT, 4 blocks/CU) -------------
__global__ __launch_bounds__(256) void k_attn(const __hip_bfloat16* __restrict__ Qp,
    const __hip_bfloat16* __restrict__ Kp, const __hip_bfloat16* __restrict__ Vt,
    __hip_bfloat16* __restrict__ Ob) {
  __shared__ alignas(16) __hip_bfloat16 lK[2][64 * 32];   // 4KB each
  __shared__ alignas(16) __hip_bfloat16 lV[2][32 * 64];   // 4KB each
  __shared__ alignas(16) __hip_bfloat16 Plds[4][16][72];
  const int lin = blockIdx.x;           // 0..1023
  const int xcd = lin & 7;
  const int idx = lin >> 3;             // 0..127
  const int h = xcd * 2 + (idx & 1);    // 2 heads per XCD
  const int qb = 63 - (idx >> 1);       // DESCENDING: big blocks first (LPT)
  const int nt = qb + 1;
  const int tid = threadIdx.x;
  const int lane = tid & 63, w = tid >> 6;
  const int g = lane >> 4, c = lane & 15;
  // staging source mapping (inverse of the LDS read permutation)
  const int krow = (tid >> 6) * 16 + (tid & 15);
  const int kcol = ((tid >> 4) & 3) * 8;
  const int vrow = ((tid >> 6) & 1) * 16 + (tid & 15);
  const int vcol = ((tid >> 7) & 1) * 32 + ((tid >> 4) & 3) * 8;
  const __hip_bfloat16* Kh = Kp + (size_t)h * TT * 32 + (size_t)krow * 32 + kcol;
  const __hip_bfloat16* Vh = Vt + (size_t)h * 32 * TT + (size_t)vrow * TT + vcol;
  const f32x4 zz = {0.f, 0.f, 0.f, 0.f};

  const int qrow = qb * 64 + w * 16 + c;
  const short8 qf =
      *reinterpret_cast<const short8*>(Qp + ((size_t)h * TT + qrow) * 32 + 8 * g);
  f32x4 o0 = zz, o1 = zz;
  float mst = -1e30f, lsum = 0.f;
  int cur = 0;
  __builtin_amdgcn_global_load_lds(
      (const __attribute__((address_space(1))) void*)Kh,
      (__attribute__((address_space(3))) void*)(lK[0] + tid * 8), 16, 0, 0);
  __builtin_amdgcn_global_load_lds(
      (const __attribute__((address_space(1))) void*)Vh,
      (__attribute__((address_space(3))) void*)(lV[0] + tid * 8), 16, 0, 0);

  for (int it = 0; it < nt; ++it) {
    __syncthreads();  // buf[cur] staged + all waves done with buf[cur^1]
    if (it + 1 < nt) {
      const int kv1 = (it + 1) * 64;
      __builtin_amdgcn_global_load_lds(
          (const __attribute__((address_space(1))) void*)(Kh + (size_t)kv1 * 32),
          (__attribute__((address_space(3))) void*)(lK[cur ^ 1] + tid * 8), 16, 0, 0);
      __builtin_amdgcn_global_load_lds(
          (const __attribute__((address_space(1))) void*)(Vh + kv1),
          (__attribute__((address_space(3))) void*)(lV[cur ^ 1] + tid * 8), 16, 0, 0);
    }
    // K fragments: addr = base + lane*16 (conflict-free)
    const char* kb = (const char*)lK[cur];
    short8 kf[4];
#pragma unroll
    for (int ct = 0; ct < 4; ++ct)
      kf[ct] = *reinterpret_cast<const short8*>(kb + ct * 1024 + lane * 16);
    // V fragments: addr = base + lane*16 (conflict-free)
    const char* vb = (const char*)lV[cur];
    const short8 v00 = *reinterpret_cast<const short8*>(vb + lane * 16);
    const short8 v10 = *reinterpret_cast<const short8*>(vb + 1024 + lane * 16);
    const short8 v01 = *reinterpret_cast<const short8*>(vb + 2048 + lane * 16);
    const short8 v11 = *reinterpret_cast<const short8*>(vb + 3072 + lane * 16);
    f32x4 s[4];
#pragma unroll
    for (int ct = 0; ct < 4; ++ct)
      s[ct] = __builtin_amdgcn_mfma_f32_16x16x32_bf16(kf[ct], qf, zz, 0, 0, 0);  // swapped
    if (it == nt - 1) {  // diagonal tile: mask k > q
#pragma unroll
      for (int ct = 0; ct < 4; ++ct)
#pragma unroll
        for (int j = 0; j < 4; ++j)
          if (ct * 16 + g * 4 + j > w * 16 + c) s[ct][j] = -1e30f;
    }
    // in-lane max over 16 scores
    float m01 = fmaxf(fmaxf(s[0][0], s[0][1]), fmaxf(s[0][2], s[0][3]));
    float m23 = fmaxf(fmaxf(s[1][0], s[1][1]), fmaxf(s[1][2], s[1][3]));
    float m45 = fmaxf(fmaxf(s[2][0], s[2][1]), fmaxf(s[2][2], s[2][3]));
    float m67 = fmaxf(fmaxf(s[3][0], s[3][1]), fmaxf(s[3][2], s[3][3]));
    float pm_ = fmaxf(fmaxf(m01, m23), fmaxf(m45, m67));
    if (__any(pm_ > mst + 8.0f)) {  // defer-max
      float pm2 = fmaxf(pm_, __shfl_xor(pm_, 16, 64));
      pm2 = fmaxf(pm2, __shfl_xor(pm2, 32, 64));
      const float nm = fmaxf(mst, pm2);
      const float alpha = exp2f(mst - nm);
      mst = nm;
      lsum *= alpha;
#pragma unroll
      for (int j = 0; j < 4; ++j) { o0[j] *= alpha; o1[j] *= alpha; }
    }
    float ts = 0.f;
#pragma unroll
    for (int ct = 0; ct < 4; ++ct) {
#pragma unroll
      for (int j = 0; j < 4; ++j) s[ct][j] = exp2f(s[ct][j] - mst);
      ts += (s[ct][0] + s[ct][1]) + (s[ct][2] + s[ct][3]);
    }
    lsum += ts;
    // P -> LDS (packed bf16 pairs), per-wave private slice (2-way max: free)
#pragma unroll
    for (int ct = 0; ct < 4; ++ct) {
      float2 p01; p01.x = s[ct][0]; p01.y = s[ct][1];
      float2 p23; p23.x = s[ct][2]; p23.y = s[ct][3];
      __hip_bfloat162 b01 = __float22bfloat162_rn(p01);
      __hip_bfloat162 b23 = __float22bfloat162_rn(p23);
      *reinterpret_cast<__hip_bfloat162*>(&Plds[w][c][ct * 16 + g * 4]) = b01;
      *reinterpret_cast<__hip_bfloat162*>(&Plds[w][c][ct * 16 + g * 4 + 2]) = b23;
    }
    const short8 pf0 = *reinterpret_cast<const short8*>(&Plds[w][c][8 * g]);
    const short8 pf1 = *reinterpret_cast<const short8*>(&Plds[w][c][32 + 8 * g]);
    // O^T: C col = q-row = lane c
    o0 = __builtin_amdgcn_mfma_f32_16x16x32_bf16(v00, pf0, o0, 0, 0, 0);
    o0 = __builtin_amdgcn_mfma_f32_16x16x32_bf16(v01, pf1, o0, 0, 0, 0);
    o1 = __builtin_amdgcn_mfma_f32_16x16x32_bf16(v10, pf0, o1, 0, 0, 0);
    o1 = __builtin_amdgcn_mfma_f32_16x16x32_bf16(v11, pf1, o1, 0, 0, 0);
    cur ^= 1;
  }
  // final lsum reduce across g-lanes of row c; write Ob
  lsum += __shfl_xor(lsum, 16, 64);
  lsum += __shfl_xor(lsum, 32, 64);
  const float inv = 1.0f / lsum;
  __hip_bfloat16* dst = Ob + (size_t)qrow * DATTN + h * 32;
  short4v w0, w1;
#pragma unroll
  for (int j = 0; j < 4; ++j) { w0[j] = f2bf(o0[j] * inv); w1[j] = f2bf(o1[j] * inv); }
  *reinterpret_cast<short4v*>(dst + g * 4) = w0;
  *reinterpret_cast<short4v*>(dst + 16 + g * 4) = w1;
}

extern "C" void kernel_launch(void* const* d_in, const int* in_sizes, int n_in,
                              void* d_out, int out_size, void* d_ws, size_t ws_size,
                              hipStream_t stream) {
  const float* x   = (const float*)d_in[0];
  const float* qsw = (const float*)d_in[1];
  const float* ksw = (const float*)d_in[2];
  const float* qgw = (const float*)d_in[3];
  const float* kgw = (const float*)d_in[4];
  const float* vw  = (const float*)d_in[5];
  const float* ow  = (const float*)d_in[6];
  const float* ls  = (const float*)d_in[7];
  const int* posp  = (const int*)d_in[9];

  size_t off = 0;
  auto alloc = [&](size_t bytes) {
    char* p = (char*)d_ws + off;
    off += (bytes + 255) & ~(size_t)255;
    return (void*)p;
  };
  __hip_bfloat16* Xbf  = (__hip_bfloat16*)alloc((size_t)TT * DM * 2);
  __hip_bfloat16* Wcat = (__hip_bfloat16*)alloc((size_t)NPROJ * DM * 2);
  __hip_bfloat16* OW   = (__hip_bfloat16*)alloc((size_t)DM * DATTN * 2);
  __hip_bfloat16* proj = (__hip_bfloat16*)alloc((size_t)TT * NPROJ * 2);
  __hip_bfloat16* Qp   = (__hip_bfloat16*)alloc((size_t)NH * TT * 32 * 2);
  __hip_bfloat16* Kpk  = (__hip_bfloat16*)alloc((size_t)NH * TT * 32 * 2);
  __hip_bfloat16* Vt   = (__hip_bfloat16*)alloc((size_t)NH * 32 * TT * 2);
  __hip_bfloat16* Ob   = (__hip_bfloat16*)alloc((size_t)TT * DATTN * 2);

  k_prep<<<dim3(NB_X + NB_OW + NB_WC), 256, 0, stream>>>(x, ow, qsw, ksw, qgw, kgw, vw,
                                                         Xbf, OW, Wcat);
  k_gemm_bt<1><<<dim3(TT / 64, NPROJ / 128), 256, 0, stream>>>(Xbf, Wcat, (void*)proj,
                                                               TT, NPROJ, DM);
  k_rope_pack<<<dim3(TT * NH / 256), 256, 0, stream>>>(proj, ls, posp, Qp, Kpk, Vt);
  k_attn<<<dim3(1024), 256, 0, stream>>>(Qp, Kpk, Vt, Ob);
  k_gemm_bt<0><<<dim3(TT / 64, DM / 128), 256, 0, stream>>>(Ob, OW, (void*)d_out,
                                                            TT, DM, DATTN);
}

// Round 20
// 112.135 us; speedup vs baseline: 1.3564x; 1.0582x over previous
//
#include <hip/hip_runtime.h>
#include <hip/hip_bf16.h>

typedef __attribute__((ext_vector_type(8))) short short8;
typedef __attribute__((ext_vector_type(4))) short short4v;
typedef __attribute__((ext_vector_type(4))) float f32x4;

#define TT 4096
#define DM 1024
#define NH 16
#define NPROJ 1280   // 128 qs + 128 ks + 256 qg + 256 kg + 512 v
#define DATTN 512

static __device__ __forceinline__ short f2bf(float f) {
  __hip_bfloat16 h = __float2bfloat16(f);
  return *reinterpret_cast<short*>(&h);
}

// ---------------- fused prep: x->bf16, ow->bf16, wcat concat (one launch) ----------------
#define NB_X   (TT * DM / 4 / 256)        // 4096 blocks
#define NB_OW  (DM * DATTN / 4 / 256)     // 512 blocks
#define NB_WC  (NPROJ * DM / 4 / 256)     // 1280 blocks
__global__ __launch_bounds__(256) void k_prep(const float* __restrict__ x,
    const float* __restrict__ ow, const float* __restrict__ qs, const float* __restrict__ ks,
    const float* __restrict__ qg, const float* __restrict__ kg, const float* __restrict__ vw,
    __hip_bfloat16* __restrict__ Xbf, __hip_bfloat16* __restrict__ OW,
    __hip_bfloat16* __restrict__ Wcat) {
  const int b = blockIdx.x;
  if (b < NB_X) {
    const int i = b * 256 + threadIdx.x;
    float4 v = reinterpret_cast<const float4*>(x)[i];
    short4v o;
    o[0] = f2bf(v.x); o[1] = f2bf(v.y); o[2] = f2bf(v.z); o[3] = f2bf(v.w);
    reinterpret_cast<short4v*>(Xbf)[i] = o;
  } else if (b < NB_X + NB_OW) {
    const int i = (b - NB_X) * 256 + threadIdx.x;
    float4 v = reinterpret_cast<const float4*>(ow)[i];
    short4v o;
    o[0] = f2bf(v.x); o[1] = f2bf(v.y); o[2] = f2bf(v.z); o[3] = f2bf(v.w);
    reinterpret_cast<short4v*>(OW)[i] = o;
  } else {
    const int i = (b - NB_X - NB_OW) * 256 + threadIdx.x;
    const int idx = i * 4;
    const int row = idx >> 10;
    const int col = idx & 1023;
    const float* src;
    if (row < 128)      src = qs + (size_t)row * DM;
    else if (row < 256) src = ks + (size_t)(row - 128) * DM;
    else if (row < 512) src = qg + (size_t)(row - 256) * DM;
    else if (row < 768) src = kg + (size_t)(row - 512) * DM;
    else                src = vw + (size_t)(row - 768) * DM;
    float4 v = *reinterpret_cast<const float4*>(src + col);
    short4v o;
    o[0] = f2bf(v.x); o[1] = f2bf(v.y); o[2] = f2bf(v.z); o[3] = f2bf(v.w);
    *reinterpret_cast<short4v*>(Wcat + idx) = o;
  }
}

// ---------------- bf16 GEMM, B^T layout, BM=64 BN=128 BK=64, double-buffered ----------
// EPI=0: plain fp32 C write (out projection).
// EPI=1: fused RoPE/pack epilogue (proj GEMM): blockIdx.y selects region --
//   y=0: qs -> Qp dims 0..8 (x qscale) + zero pads dims 24..32
//   y=1: ks -> Kp dims 0..8 + zero pads
//   y=2,3: qg -> Qp dims 8..24, rope via lane^8 shuffle, x qscale
//   y=4,5: kg -> Kp dims 8..24, rope
//   y=6..9: v -> Vt[(h*32+d)*TT + t], 4 consecutive t per 8B store
template<int EPI>
__global__ __launch_bounds__(256) void k_gemm_bt(const __hip_bfloat16* __restrict__ A,
    const __hip_bfloat16* __restrict__ B, void* __restrict__ Cv, int M, int N, int K,
    __hip_bfloat16* __restrict__ Qp, __hip_bfloat16* __restrict__ Kp,
    __hip_bfloat16* __restrict__ Vt, const float* __restrict__ ls,
    const int* __restrict__ posp) {
  __shared__ alignas(16) __hip_bfloat16 lA[2][2][64 * 32];    // [buf][kk]
  __shared__ alignas(16) __hip_bfloat16 lB[2][2][128 * 32];   // [buf][kk]
  const int tid = threadIdx.x;
  const int lane = tid & 63;
  const int wid = tid >> 6;
  const int m0 = blockIdx.x * 64, n0 = blockIdx.y * 128;
  const int wm = (wid >> 1) * 32, wn = (wid & 1) * 64;
  const int srow = tid >> 2;          // 0..63
  const int scol = (tid & 3) * 8;     // bf16 elements within a 32-col panel
  const int fr = lane & 15, fk = (lane >> 4) * 8;
  f32x4 acc[2][4];
  const f32x4 zz = {0.f, 0.f, 0.f, 0.f};
#pragma unroll
  for (int m = 0; m < 2; ++m)
#pragma unroll
    for (int n = 0; n < 4; ++n) acc[m][n] = zz;

  auto stage = [&](int kt, int buf) {
#pragma unroll
    for (int kk = 0; kk < 2; ++kk) {
      const int kcol = kt + kk * 32 + scol;
      const __hip_bfloat16* ga0 = A + (size_t)(m0 + srow) * K + kcol;
      const __hip_bfloat16* gb0 = B + (size_t)(n0 + srow) * K + kcol;
      const __hip_bfloat16* gb1 = B + (size_t)(n0 + 64 + srow) * K + kcol;
      __builtin_amdgcn_global_load_lds((const __attribute__((address_space(1))) void*)ga0,
          (__attribute__((address_space(3))) void*)(lA[buf][kk] + srow * 32 + scol), 16, 0, 0);
      __builtin_amdgcn_global_load_lds((const __attribute__((address_space(1))) void*)gb0,
          (__attribute__((address_space(3))) void*)(lB[buf][kk] + srow * 32 + scol), 16, 0, 0);
      __builtin_amdgcn_global_load_lds((const __attribute__((address_space(1))) void*)gb1,
          (__attribute__((address_space(3))) void*)(lB[buf][kk] + (64 + srow) * 32 + scol), 16, 0, 0);
    }
  };
  stage(0, 0);
  int buf = 0;
  for (int kt = 0; kt < K; kt += 64) {
    __syncthreads();   // staging of buf complete; prev reads of buf^1 done
    if (kt + 64 < K) stage(kt + 64, buf ^ 1);
#pragma unroll
    for (int kk = 0; kk < 2; ++kk) {
      short8 af[2], bfr[4];
#pragma unroll
      for (int m = 0; m < 2; ++m)
        af[m] = *reinterpret_cast<const short8*>(lA[buf][kk] + (wm + m * 16 + fr) * 32 + fk);
#pragma unroll
      for (int n = 0; n < 4; ++n)
        bfr[n] = *reinterpret_cast<const short8*>(lB[buf][kk] + (wn + n * 16 + fr) * 32 + fk);
#pragma unroll
      for (int m = 0; m < 2; ++m)
#pragma unroll
        for (int n = 0; n < 4; ++n)
          acc[m][n] = __builtin_amdgcn_mfma_f32_16x16x32_bf16(af[m], bfr[n], acc[m][n], 0, 0, 0);
    }
    buf ^= 1;
  }
  const int cr = (lane >> 4) * 4, cc = lane & 15;
  if (EPI == 0) {
#pragma unroll
    for (int m = 0; m < 2; ++m)
#pragma unroll
      for (int n = 0; n < 4; ++n)
#pragma unroll
        for (int j = 0; j < 4; ++j) {
          const int row = m0 + wm + m * 16 + cr + j;
          const int col = n0 + wn + n * 16 + cc;
          ((float*)Cv)[(size_t)row * N + col] = acc[m][n][j];
        }
    return;
  }
  // ---- EPI=1: fused RoPE/pack epilogue ----
  const int y = blockIdx.y;
  const float QSC = 0.20412414523193154f * 1.4426950408889634f;  // 1/sqrt(24)*log2(e)
  if (y < 2) {
    __hip_bfloat16* P = (y == 0) ? Qp : Kp;
    const __hip_bfloat16 zb = __float2bfloat16(0.f);
#pragma unroll
    for (int n = 0; n < 4; ++n) {
      const int cl = wn + n * 16 + cc;        // 0..127
      const int h = cl >> 3, d = cl & 7;
      const float sc = (y == 0) ? QSC * __expf(ls[h]) : 1.0f;
#pragma unroll
      for (int m = 0; m < 2; ++m)
#pragma unroll
        for (int j = 0; j < 4; ++j) {
          const int row = m0 + wm + m * 16 + cr + j;
          __hip_bfloat16* base = P + ((size_t)h * TT + row) * 32;
          base[d] = __float2bfloat16(acc[m][n][j] * sc);
          base[24 + d] = zb;
        }
    }
  } else if (y < 6) {
    const int isQ = (y < 4);
    __hip_bfloat16* P = isQ ? Qp : Kp;
    const int segbase = isQ ? 256 : 512;
    const float invf[8] = {1.0f, 0.31622776601683794f, 0.1f, 0.031622776601683794f,
                           0.01f, 0.0031622776601683794f, 0.001f, 0.00031622776601683794f};
    const float fr_ = invf[cc & 7];
    const float pofs = (float)posp[0];
    const int lo = (cc < 8);
    const int d = 8 + cc;                     // 8..24
#pragma unroll
    for (int n = 0; n < 4; ++n) {
      const int h = (y * 128 + wn + n * 16 - segbase) >> 4;
      const float sc = isQ ? QSC * __expf(ls[h]) : 1.0f;
#pragma unroll
      for (int m = 0; m < 2; ++m)
#pragma unroll
        for (int j = 0; j < 4; ++j) {
          const int row = m0 + wm + m * 16 + cr + j;
          const float own = acc[m][n][j];
          const float oth = __shfl_xor(own, 8, 64);
          float ss, cs;
          __sincosf((row + pofs) * fr_, &ss, &cs);
          const float out = lo ? (own * cs - oth * ss) : (oth * ss + own * cs);
          P[((size_t)h * TT + row) * 32 + d] = __float2bfloat16(out * sc);
        }
    }
  } else {
#pragma unroll
    for (int n = 0; n < 4; ++n) {
      const int local = y * 128 + wn + n * 16 - 768 + cc;   // 0..511
      const int h = local >> 5, d = local & 31;
#pragma unroll
      for (int m = 0; m < 2; ++m) {
        short4v pk;
#pragma unroll
        for (int j = 0; j < 4; ++j) pk[j] = f2bf(acc[m][n][j]);
        const int row0 = m0 + wm + m * 16 + cr;   // multiple of 4
        *reinterpret_cast<short4v*>(Vt + ((size_t)h * 32 + d) * TT + row0) = pk;
      }
    }
  }
}

// ---------------- causal flash attention (R11: LDS K/V, LPT, 4 blocks/CU) -------------
__global__ __launch_bounds__(256) void k_attn(const __hip_bfloat16* __restrict__ Qp,
    const __hip_bfloat16* __restrict__ Kp, const __hip_bfloat16* __restrict__ Vt,
    __hip_bfloat16* __restrict__ Ob) {
  __shared__ alignas(16) __hip_bfloat16 lK[2][64 * 32];   // 4KB each
  __shared__ alignas(16) __hip_bfloat16 lV[2][32 * 64];   // 4KB each
  __shared__ alignas(16) __hip_bfloat16 Plds[4][16][72];
  const int lin = blockIdx.x;           // 0..1023
  const int xcd = lin & 7;
  const int idx = lin >> 3;             // 0..127
  const int h = xcd * 2 + (idx & 1);    // 2 heads per XCD
  const int qb = 63 - (idx >> 1);       // DESCENDING: big blocks first (LPT)
  const int nt = qb + 1;
  const int tid = threadIdx.x;
  const int lane = tid & 63, w = tid >> 6;
  const int g = lane >> 4, c = lane & 15;
  // staging source mapping (inverse of the LDS read permutation)
  const int krow = (tid >> 6) * 16 + (tid & 15);
  const int kcol = ((tid >> 4) & 3) * 8;
  const int vrow = ((tid >> 6) & 1) * 16 + (tid & 15);
  const int vcol = ((tid >> 7) & 1) * 32 + ((tid >> 4) & 3) * 8;
  const __hip_bfloat16* Kh = Kp + (size_t)h * TT * 32 + (size_t)krow * 32 + kcol;
  const __hip_bfloat16* Vh = Vt + (size_t)h * 32 * TT + (size_t)vrow * TT + vcol;
  const f32x4 zz = {0.f, 0.f, 0.f, 0.f};

  const int qrow = qb * 64 + w * 16 + c;
  const short8 qf =
      *reinterpret_cast<const short8*>(Qp + ((size_t)h * TT + qrow) * 32 + 8 * g);
  f32x4 o0 = zz, o1 = zz;
  float mst = -1e30f, lsum = 0.f;
  int cur = 0;
  __builtin_amdgcn_global_load_lds(
      (const __attribute__((address_space(1))) void*)Kh,
      (__attribute__((address_space(3))) void*)(lK[0] + tid * 8), 16, 0, 0);
  __builtin_amdgcn_global_load_lds(
      (const __attribute__((address_space(1))) void*)Vh,
      (__attribute__((address_space(3))) void*)(lV[0] + tid * 8), 16, 0, 0);

  for (int it = 0; it < nt; ++it) {
    __syncthreads();  // buf[cur] staged + all waves done with buf[cur^1]
    if (it + 1 < nt) {
      const int kv1 = (it + 1) * 64;
      __builtin_amdgcn_global_load_lds(
          (const __attribute__((address_space(1))) void*)(Kh + (size_t)kv1 * 32),
          (__attribute__((address_space(3))) void*)(lK[cur ^ 1] + tid * 8), 16, 0, 0);
      __builtin_amdgcn_global_load_lds(
          (const __attribute__((address_space(1))) void*)(Vh + kv1),
          (__attribute__((address_space(3))) void*)(lV[cur ^ 1] + tid * 8), 16, 0, 0);
    }
    // K fragments: addr = base + lane*16 (conflict-free)
    const char* kb = (const char*)lK[cur];
    short8 kf[4];
#pragma unroll
    for (int ct = 0; ct < 4; ++ct)
      kf[ct] = *reinterpret_cast<const short8*>(kb + ct * 1024 + lane * 16);
    // V fragments: addr = base + lane*16 (conflict-free)
    const char* vb = (const char*)lV[cur];
    const short8 v00 = *reinterpret_cast<const short8*>(vb + lane * 16);
    const short8 v10 = *reinterpret_cast<const short8*>(vb + 1024 + lane * 16);
    const short8 v01 = *reinterpret_cast<const short8*>(vb + 2048 + lane * 16);
    const short8 v11 = *reinterpret_cast<const short8*>(vb + 3072 + lane * 16);
    f32x4 s[4];
#pragma unroll
    for (int ct = 0; ct < 4; ++ct)
      s[ct] = __builtin_amdgcn_mfma_f32_16x16x32_bf16(kf[ct], qf, zz, 0, 0, 0);  // swapped
    if (it == nt - 1) {  // diagonal tile: mask k > q
#pragma unroll
      for (int ct = 0; ct < 4; ++ct)
#pragma unroll
        for (int j = 0; j < 4; ++j)
          if (ct * 16 + g * 4 + j > w * 16 + c) s[ct][j] = -1e30f;
    }
    // in-lane max over 16 scores
    float m01 = fmaxf(fmaxf(s[0][0], s[0][1]), fmaxf(s[0][2], s[0][3]));
    float m23 = fmaxf(fmaxf(s[1][0], s[1][1]), fmaxf(s[1][2], s[1][3]));
    float m45 = fmaxf(fmaxf(s[2][0], s[2][1]), fmaxf(s[2][2], s[2][3]));
    float m67 = fmaxf(fmaxf(s[3][0], s[3][1]), fmaxf(s[3][2], s[3][3]));
    float pm_ = fmaxf(fmaxf(m01, m23), fmaxf(m45, m67));
    if (__any(pm_ > mst + 8.0f)) {  // defer-max
      float pm2 = fmaxf(pm_, __shfl_xor(pm_, 16, 64));
      pm2 = fmaxf(pm2, __shfl_xor(pm2, 32, 64));
      const float nm = fmaxf(mst, pm2);
      const float alpha = exp2f(mst - nm);
      mst = nm;
      lsum *= alpha;
#pragma unroll
      for (int j = 0; j < 4; ++j) { o0[j] *= alpha; o1[j] *= alpha; }
    }
    float ts = 0.f;
#pragma unroll
    for (int ct = 0; ct < 4; ++ct) {
#pragma unroll
      for (int j = 0; j < 4; ++j) s[ct][j] = exp2f(s[ct][j] - mst);
      ts += (s[ct][0] + s[ct][1]) + (s[ct][2] + s[ct][3]);
    }
    lsum += ts;
    // P -> LDS (packed bf16 pairs), per-wave private slice (2-way max: free)
#pragma unroll
    for (int ct = 0; ct < 4; ++ct) {
      float2 p01; p01.x = s[ct][0]; p01.y = s[ct][1];
      float2 p23; p23.x = s[ct][2]; p23.y = s[ct][3];
      __hip_bfloat162 b01 = __float22bfloat162_rn(p01);
      __hip_bfloat162 b23 = __float22bfloat162_rn(p23);
      *reinterpret_cast<__hip_bfloat162*>(&Plds[w][c][ct * 16 + g * 4]) = b01;
      *reinterpret_cast<__hip_bfloat162*>(&Plds[w][c][ct * 16 + g * 4 + 2]) = b23;
    }
    const short8 pf0 = *reinterpret_cast<const short8*>(&Plds[w][c][8 * g]);
    const short8 pf1 = *reinterpret_cast<const short8*>(&Plds[w][c][32 + 8 * g]);
    // O^T: C col = q-row = lane c
    o0 = __builtin_amdgcn_mfma_f32_16x16x32_bf16(v00, pf0, o0, 0, 0, 0);
    o0 = __builtin_amdgcn_mfma_f32_16x16x32_bf16(v01, pf1, o0, 0, 0, 0);
    o1 = __builtin_amdgcn_mfma_f32_16x16x32_bf16(v10, pf0, o1, 0, 0, 0);
    o1 = __builtin_amdgcn_mfma_f32_16x16x32_bf16(v11, pf1, o1, 0, 0, 0);
    cur ^= 1;
  }
  // final lsum reduce across g-lanes of row c; write Ob
  lsum += __shfl_xor(lsum, 16, 64);
  lsum += __shfl_xor(lsum, 32, 64);
  const float inv = 1.0f / lsum;
  __hip_bfloat16* dst = Ob + (size_t)qrow * DATTN + h * 32;
  short4v w0, w1;
#pragma unroll
  for (int j = 0; j < 4; ++j) { w0[j] = f2bf(o0[j] * inv); w1[j] = f2bf(o1[j] * inv); }
  *reinterpret_cast<short4v*>(dst + g * 4) = w0;
  *reinterpret_cast<short4v*>(dst + 16 + g * 4) = w1;
}

extern "C" void kernel_launch(void* const* d_in, const int* in_sizes, int n_in,
                              void* d_out, int out_size, void* d_ws, size_t ws_size,
                              hipStream_t stream) {
  const float* x   = (const float*)d_in[0];
  const float* qsw = (const float*)d_in[1];
  const float* ksw = (const float*)d_in[2];
  const float* qgw = (const float*)d_in[3];
  const float* kgw = (const float*)d_in[4];
  const float* vw  = (const float*)d_in[5];
  const float* ow  = (const float*)d_in[6];
  const float* ls  = (const float*)d_in[7];
  const int* posp  = (const int*)d_in[9];

  size_t off = 0;
  auto alloc = [&](size_t bytes) {
    char* p = (char*)d_ws + off;
    off += (bytes + 255) & ~(size_t)255;
    return (void*)p;
  };
  __hip_bfloat16* Xbf  = (__hip_bfloat16*)alloc((size_t)TT * DM * 2);
  __hip_bfloat16* Wcat = (__hip_bfloat16*)alloc((size_t)NPROJ * DM * 2);
  __hip_bfloat16* OW   = (__hip_bfloat16*)alloc((size_t)DM * DATTN * 2);
  __hip_bfloat16* Qp   = (__hip_bfloat16*)alloc((size_t)NH * TT * 32 * 2);
  __hip_bfloat16* Kpk  = (__hip_bfloat16*)alloc((size_t)NH * TT * 32 * 2);
  __hip_bfloat16* Vt   = (__hip_bfloat16*)alloc((size_t)NH * 32 * TT * 2);
  __hip_bfloat16* Ob   = (__hip_bfloat16*)alloc((size_t)TT * DATTN * 2);

  k_prep<<<dim3(NB_X + NB_OW + NB_WC), 256, 0, stream>>>(x, ow, qsw, ksw, qgw, kgw, vw,
                                                         Xbf, OW, Wcat);
  k_gemm_bt<1><<<dim3(TT / 64, NPROJ / 128), 256, 0, stream>>>(Xbf, Wcat, nullptr,
      TT, NPROJ, DM, Qp, Kpk, Vt, ls, posp);
  k_attn<<<dim3(1024), 256, 0, stream>>>(Qp, Kpk, Vt, Ob);
  k_gemm_bt<0><<<dim3(TT / 64, DM / 128), 256, 0, stream>>>(Ob, OW, (void*)d_out,
      TT, DM, DATTN, nullptr, nullptr, nullptr, nullptr, nullptr);
}